// Round 1
// baseline (2241.041 us; speedup 1.0000x reference)
//
#include <hip/hip_runtime.h>

// Problem constants: B=64, Cin=P=64, H=W=64, mid C=16, offsets C=18, K=3x3
// BN n = B*H*W = 262144
#define BN_N 262144.0f

// ---------------------------------------------------------------- conv1: 3x3, 64->64, pad 1
__global__ __launch_bounds__(256) void conv1_k(const float* __restrict__ x,
                                               const float* __restrict__ w,   // (64,64,3,3)
                                               float* __restrict__ out) {     // raw (64,64,64,64)
  const int tile = blockIdx.x;                 // 16 tiles of 16x16
  const int ty0 = (tile >> 2) * 16, tx0 = (tile & 3) * 16;
  const int ocg = blockIdx.y;                  // 4 groups of 16 oc
  const int b = blockIdx.z;
  const int tid = threadIdx.x;

  __shared__ float s_in[8][324];               // 8 ch x 18x18
  __shared__ float s_w[16 * 8 * 12];           // [oc][c][k], k padded 9->12

  float acc[16];
#pragma unroll
  for (int i = 0; i < 16; ++i) acc[i] = 0.f;

  const int py = tid >> 4, px = tid & 15;
  const int oy = ty0 + py, ox = tx0 + px;

  for (int cb = 0; cb < 8; ++cb) {
    for (int i = tid; i < 8 * 324; i += 256) {
      int c = i / 324, r = i - c * 324;
      int yy = r / 18, xx = r - yy * 18;
      int gy = ty0 + yy - 1, gx = tx0 + xx - 1;
      float v = 0.f;
      if ((unsigned)gy < 64u && (unsigned)gx < 64u)
        v = x[((b * 64 + cb * 8 + c) << 12) + (gy << 6) + gx];
      s_in[c][r] = v;
    }
    for (int i = tid; i < 1152; i += 256) {     // 16*8*9
      int oc = i / 72, rem = i - oc * 72;       // rem = c*9+k
      int c = rem / 9, k = rem - c * 9;
      s_w[(oc * 8 + c) * 12 + k] = w[(ocg * 16 + oc) * 576 + cb * 72 + rem];
    }
    __syncthreads();
#pragma unroll
    for (int c = 0; c < 8; ++c) {
      float v[9];
#pragma unroll
      for (int ky = 0; ky < 3; ++ky)
#pragma unroll
        for (int kx = 0; kx < 3; ++kx)
          v[ky * 3 + kx] = s_in[c][(py + ky) * 18 + px + kx];
#pragma unroll
      for (int oc = 0; oc < 16; ++oc) {
        const float* wp = &s_w[(oc * 8 + c) * 12];
        float4 wa = *(const float4*)wp;
        float4 wb = *(const float4*)(wp + 4);
        float w8 = wp[8];
        acc[oc] += wa.x * v[0] + wa.y * v[1] + wa.z * v[2] + wa.w * v[3]
                 + wb.x * v[4] + wb.y * v[5] + wb.z * v[6] + wb.w * v[7]
                 + w8 * v[8];
      }
    }
    __syncthreads();
  }
#pragma unroll
  for (int oc = 0; oc < 16; ++oc)
    out[((b * 64 + ocg * 16 + oc) << 12) + (oy << 6) + ox] = acc[oc];
}

// ---------------------------------------------------------------- per-channel sum/sumsq (NCHW, HW=4096)
__global__ __launch_bounds__(256) void stats_k(const float* __restrict__ src, int C,
                                               float* __restrict__ sum, float* __restrict__ sq) {
  int bi = blockIdx.x;
  int c = bi % C, b = bi / C;
  const float* p = src + (((long)b * C + c) << 12);
  float s = 0.f, s2 = 0.f;
  for (int i = threadIdx.x; i < 4096; i += 256) {
    float v = p[i];
    s += v; s2 += v * v;
  }
#pragma unroll
  for (int off = 32; off > 0; off >>= 1) {
    s += __shfl_down(s, off, 64);
    s2 += __shfl_down(s2, off, 64);
  }
  __shared__ float ls[4], ls2[4];
  int lane = threadIdx.x & 63, wv = threadIdx.x >> 6;
  if (lane == 0) { ls[wv] = s; ls2[wv] = s2; }
  __syncthreads();
  if (threadIdx.x == 0) {
    atomicAdd(&sum[c], ls[0] + ls[1] + ls[2] + ls[3]);
    atomicAdd(&sq[c],  ls2[0] + ls2[1] + ls2[2] + ls2[3]);
  }
}

// ---------------------------------------------------------------- conv2: 1x1 64->16, BN1+relu fused on input
__global__ __launch_bounds__(256) void conv2_k(const float* __restrict__ h1raw,
                                               const float* __restrict__ w2,   // (16,64)
                                               const float* __restrict__ sum1, const float* __restrict__ sq1,
                                               const float* __restrict__ g1, const float* __restrict__ b1,
                                               float* __restrict__ out) {      // raw (64,16,64,64)
  __shared__ float s_wt[64 * 16];   // transposed [c][o]
  __shared__ float s_scale[64], s_shift[64];
  int tid = threadIdx.x;
  for (int i = tid; i < 1024; i += 256) {
    int o = i >> 6, c = i & 63;
    s_wt[c * 16 + o] = w2[i];
  }
  if (tid < 64) {
    float m = sum1[tid] / BN_N;
    float var = sq1[tid] / BN_N - m * m;
    float sc = g1[tid] * rsqrtf(var + 1e-5f);
    s_scale[tid] = sc;
    s_shift[tid] = b1[tid] - m * sc;
  }
  __syncthreads();
  int p = blockIdx.x * 256 + tid;
  int b = p >> 12, r = p & 4095;
  const float* src = h1raw + (b << 18) + r;
  float acc[16];
#pragma unroll
  for (int o = 0; o < 16; ++o) acc[o] = 0.f;
  for (int c = 0; c < 64; ++c) {
    float v = src[c << 12];
    v = fmaxf(v * s_scale[c] + s_shift[c], 0.f);
    const float* wp = &s_wt[c * 16];
    float4 w0 = *(const float4*)wp;
    float4 w1 = *(const float4*)(wp + 4);
    float4 w2v = *(const float4*)(wp + 8);
    float4 w3v = *(const float4*)(wp + 12);
    acc[0] += w0.x * v;  acc[1] += w0.y * v;  acc[2] += w0.z * v;  acc[3] += w0.w * v;
    acc[4] += w1.x * v;  acc[5] += w1.y * v;  acc[6] += w1.z * v;  acc[7] += w1.w * v;
    acc[8] += w2v.x * v; acc[9] += w2v.y * v; acc[10] += w2v.z * v; acc[11] += w2v.w * v;
    acc[12] += w3v.x * v; acc[13] += w3v.y * v; acc[14] += w3v.z * v; acc[15] += w3v.w * v;
  }
  float* dst = out + (b << 16) + r;
#pragma unroll
  for (int o = 0; o < 16; ++o) dst[o << 12] = acc[o];
}

// ---------------------------------------------------------------- BN2+relu -> padded NHWC h2p (64,66,66,16)
__global__ __launch_bounds__(256) void bnrelu2_k(const float* __restrict__ ws2,
                                                 const float* __restrict__ sum2, const float* __restrict__ sq2,
                                                 const float* __restrict__ g2, const float* __restrict__ b2,
                                                 float* __restrict__ h2p) {
  __shared__ float s_scale[16], s_shift[16];
  int tid = threadIdx.x;
  if (tid < 16) {
    float m = sum2[tid] / BN_N;
    float var = sq2[tid] / BN_N - m * m;
    float sc = g2[tid] * rsqrtf(var + 1e-5f);
    s_scale[tid] = sc;
    s_shift[tid] = b2[tid] - m * sc;
  }
  __syncthreads();
  int p = blockIdx.x * 256 + tid;
  int b = p >> 12, r = p & 4095;
  int y = r >> 6, xx = r & 63;
  const float* src = ws2 + (b << 16) + r;
  float vals[16];
#pragma unroll
  for (int c = 0; c < 16; ++c)
    vals[c] = fmaxf(src[c << 12] * s_scale[c] + s_shift[c], 0.f);
  float* dst = h2p + (((b * 66) + y + 1) * 66 + xx + 1) * 16;
#pragma unroll
  for (int c4 = 0; c4 < 4; ++c4)
    *(float4*)(dst + c4 * 4) = make_float4(vals[c4*4], vals[c4*4+1], vals[c4*4+2], vals[c4*4+3]);
}

// ---------------------------------------------------------------- offsets conv: 3x3 16->18 on h2p (NHWC)
__global__ __launch_bounds__(256) void offconv_k(const float* __restrict__ h2p,
                                                 const float* __restrict__ ow,  // (18,16,3,3)
                                                 const float* __restrict__ ob,  // (18,)
                                                 float* __restrict__ offs) {    // (64,18,64,64)
  const int tile = blockIdx.x;
  const int ty0 = (tile >> 2) * 16, tx0 = (tile & 3) * 16;
  const int b = blockIdx.y;
  const int tid = threadIdx.x;
  __shared__ float s_in[16][324];        // [c][18x18]
  __shared__ float s_w[18 * 16 * 12];
  for (int i = tid; i < 5184; i += 256) {  // i = pix*16 + c for coalesced NHWC read
    int pix = i >> 4, c = i & 15;
    int yy = pix / 18, xxp = pix - yy * 18;
    s_in[c][pix] = h2p[(((b * 66) + ty0 + yy) * 66 + tx0 + xxp) * 16 + c];
  }
  for (int i = tid; i < 2592; i += 256) {
    int oc = i / 144, rem = i - oc * 144;
    int c = rem / 9, k = rem - c * 9;
    s_w[(oc * 16 + c) * 12 + k] = ow[i];
  }
  __syncthreads();
  int py = tid >> 4, px = tid & 15;
  float acc[18];
#pragma unroll
  for (int o = 0; o < 18; ++o) acc[o] = ob[o];
  for (int c = 0; c < 16; ++c) {
    float v[9];
#pragma unroll
    for (int ky = 0; ky < 3; ++ky)
#pragma unroll
      for (int kx = 0; kx < 3; ++kx)
        v[ky * 3 + kx] = s_in[c][(py + ky) * 18 + px + kx];
#pragma unroll
    for (int o = 0; o < 18; ++o) {
      const float* wp = &s_w[(o * 16 + c) * 12];
      float4 wa = *(const float4*)wp;
      float4 wb = *(const float4*)(wp + 4);
      float w8 = wp[8];
      acc[o] += wa.x * v[0] + wa.y * v[1] + wa.z * v[2] + wa.w * v[3]
              + wb.x * v[4] + wb.y * v[5] + wb.z * v[6] + wb.w * v[7]
              + w8 * v[8];
    }
  }
  int r = (ty0 + py) * 64 + tx0 + px;
  float* dst = offs + (long)b * 73728 + r;
#pragma unroll
  for (int o = 0; o < 18; ++o) dst[o << 12] = acc[o];
}

// ---------------------------------------------------------------- deformable conv: bilinear sample + einsum
__global__ __launch_bounds__(256) void deform_k(const float* __restrict__ h2p,
                                                const float* __restrict__ offs,
                                                const float* __restrict__ w3,   // (16,16,9)
                                                float* __restrict__ out) {      // raw (64,16,64,64)
  __shared__ float s_w[9 * 16 * 16];      // [k][c][o]
  int tid = threadIdx.x;
  for (int i = tid; i < 2304; i += 256) {
    int o = i / 144, rem = i - o * 144;
    int c = rem / 9, k = rem - c * 9;
    s_w[(k * 16 + c) * 16 + o] = w3[i];
  }
  __syncthreads();
  int p = blockIdx.x * 256 + tid;
  int b = p >> 12, r = p & 4095;
  int y = r >> 6, x = r & 63;
  const float* offp = offs + (long)b * 73728 + r;
  const float* img = h2p + (long)b * 66 * 66 * 16;
  float acc[16];
#pragma unroll
  for (int o = 0; o < 16; ++o) acc[o] = 0.f;
#pragma unroll
  for (int k = 0; k < 9; ++k) {
    float offy = offp[k << 12];
    float offx = offp[(k + 9) << 12];
    float py = (float)(y + (k / 3)) + offy;     // (y+1) + (k/3 - 1) + off
    float px = (float)(x + (k % 3)) + offx;
    py = fminf(fmaxf(py, 0.f), 65.f);
    px = fminf(fmaxf(px, 0.f), 65.f);
    float y0f = floorf(py), x0f = floorf(px);
    int y0 = (int)y0f, x0 = (int)x0f;
    int y1 = min(y0 + 1, 65), x1 = min(x0 + 1, 65);
    float wy = py - y0f, wx = px - x0f;
    float w00 = (1.f - wy) * (1.f - wx), w01 = (1.f - wy) * wx;
    float w10 = wy * (1.f - wx),         w11 = wy * wx;
    const float* p00 = img + (y0 * 66 + x0) * 16;
    const float* p01 = img + (y0 * 66 + x1) * 16;
    const float* p10 = img + (y1 * 66 + x0) * 16;
    const float* p11 = img + (y1 * 66 + x1) * 16;
    const float* wk = &s_w[k << 8];
#pragma unroll
    for (int c4 = 0; c4 < 4; ++c4) {
      float4 a = *(const float4*)(p00 + c4 * 4);
      float4 bq = *(const float4*)(p01 + c4 * 4);
      float4 cq = *(const float4*)(p10 + c4 * 4);
      float4 dq = *(const float4*)(p11 + c4 * 4);
      float s0 = a.x * w00 + bq.x * w01 + cq.x * w10 + dq.x * w11;
      float s1 = a.y * w00 + bq.y * w01 + cq.y * w10 + dq.y * w11;
      float s2 = a.z * w00 + bq.z * w01 + cq.z * w10 + dq.z * w11;
      float s3 = a.w * w00 + bq.w * w01 + cq.w * w10 + dq.w * w11;
      const float* wc0 = wk + c4 * 64;
#pragma unroll
      for (int o = 0; o < 16; ++o)
        acc[o] += wc0[o] * s0 + wc0[16 + o] * s1 + wc0[32 + o] * s2 + wc0[48 + o] * s3;
    }
  }
  float* dst = out + (b << 16) + r;
#pragma unroll
  for (int o = 0; o < 16; ++o) dst[o << 12] = acc[o];
}

// ---------------------------------------------------------------- conv4: 3x3 16->64, BN3+relu fused on input
__global__ __launch_bounds__(256) void conv4_k(const float* __restrict__ wsd,
                                               const float* __restrict__ w4,   // (64,16,3,3)
                                               const float* __restrict__ sum3, const float* __restrict__ sq3,
                                               const float* __restrict__ g3, const float* __restrict__ b3,
                                               float* __restrict__ out) {      // raw (64,64,64,64)
  __shared__ float s_in[16][324];
  __shared__ float s_w[32 * 16 * 12];
  __shared__ float s_scale[16], s_shift[16];
  int tid = threadIdx.x;
  if (tid < 16) {
    float m = sum3[tid] / BN_N;
    float var = sq3[tid] / BN_N - m * m;
    float sc = g3[tid] * rsqrtf(var + 1e-5f);
    s_scale[tid] = sc;
    s_shift[tid] = b3[tid] - m * sc;
  }
  __syncthreads();
  const int tile = blockIdx.x;
  const int ty0 = (tile >> 2) * 16, tx0 = (tile & 3) * 16;
  const int ocg = blockIdx.y;                  // 2 groups of 32
  const int b = blockIdx.z;
  for (int i = tid; i < 16 * 324; i += 256) {
    int c = i / 324, r = i - c * 324;
    int yy = r / 18, xx = r - yy * 18;
    int gy = ty0 + yy - 1, gx = tx0 + xx - 1;
    float v = 0.f;
    if ((unsigned)gy < 64u && (unsigned)gx < 64u) {
      v = wsd[((b * 16 + c) << 12) + (gy << 6) + gx];
      v = fmaxf(v * s_scale[c] + s_shift[c], 0.f);
    }
    s_in[c][r] = v;
  }
  for (int i = tid; i < 4608; i += 256) {       // 32*16*9
    int oc = i / 144, rem = i - oc * 144;
    int c = rem / 9, k = rem - c * 9;
    s_w[(oc * 16 + c) * 12 + k] = w4[ocg * 4608 + i];
  }
  __syncthreads();
  int py = tid >> 4, px = tid & 15;
  float acc[32];
#pragma unroll
  for (int o = 0; o < 32; ++o) acc[o] = 0.f;
  for (int c = 0; c < 16; ++c) {
    float v[9];
#pragma unroll
    for (int ky = 0; ky < 3; ++ky)
#pragma unroll
      for (int kx = 0; kx < 3; ++kx)
        v[ky * 3 + kx] = s_in[c][(py + ky) * 18 + px + kx];
#pragma unroll
    for (int o = 0; o < 32; ++o) {
      const float* wp = &s_w[(o * 16 + c) * 12];
      float4 wa = *(const float4*)wp;
      float4 wb = *(const float4*)(wp + 4);
      float w8 = wp[8];
      acc[o] += wa.x * v[0] + wa.y * v[1] + wa.z * v[2] + wa.w * v[3]
              + wb.x * v[4] + wb.y * v[5] + wb.z * v[6] + wb.w * v[7]
              + w8 * v[8];
    }
  }
  int oy = ty0 + py, ox = tx0 + px;
  float* dst = out + ((b * 64 + ocg * 32) << 12) + (oy << 6) + ox;
#pragma unroll
  for (int o = 0; o < 32; ++o) dst[o << 12] = acc[o];
}

// ---------------------------------------------------------------- final: BN4 + residual + relu (in-place on out)
__global__ __launch_bounds__(256) void final_k(float* __restrict__ out,
                                               const float* __restrict__ x,
                                               const float* __restrict__ sum4, const float* __restrict__ sq4,
                                               const float* __restrict__ g4, const float* __restrict__ b4) {
  __shared__ float s_scale[64], s_shift[64];
  int tid = threadIdx.x;
  if (tid < 64) {
    float m = sum4[tid] / BN_N;
    float var = sq4[tid] / BN_N - m * m;
    float sc = g4[tid] * rsqrtf(var + 1e-5f);
    s_scale[tid] = sc;
    s_shift[tid] = b4[tid] - m * sc;
  }
  __syncthreads();
  int i = (blockIdx.x * 256 + tid) * 4;
  int c = (i >> 12) & 63;
  float4 v = *(const float4*)(out + i);
  float4 xv = *(const float4*)(x + i);
  float sc = s_scale[c], sh = s_shift[c];
  v.x = fmaxf(v.x * sc + sh + xv.x, 0.f);
  v.y = fmaxf(v.y * sc + sh + xv.y, 0.f);
  v.z = fmaxf(v.z * sc + sh + xv.z, 0.f);
  v.w = fmaxf(v.w * sc + sh + xv.w, 0.f);
  *(float4*)(out + i) = v;
}

extern "C" void kernel_launch(void* const* d_in, const int* in_sizes, int n_in,
                              void* d_out, int out_size, void* d_ws, size_t ws_size,
                              hipStream_t stream) {
  const float* x  = (const float*)d_in[0];
  const float* w1 = (const float*)d_in[1];
  const float* g1 = (const float*)d_in[2];
  const float* b1 = (const float*)d_in[3];
  const float* w2 = (const float*)d_in[4];
  const float* g2 = (const float*)d_in[5];
  const float* b2 = (const float*)d_in[6];
  const float* ow = (const float*)d_in[7];
  const float* ob = (const float*)d_in[8];
  const float* w3 = (const float*)d_in[9];
  const float* g3 = (const float*)d_in[10];
  const float* b3 = (const float*)d_in[11];
  const float* w4 = (const float*)d_in[12];
  const float* g4 = (const float*)d_in[13];
  const float* b4 = (const float*)d_in[14];
  float* out = (float*)d_out;
  float* ws = (float*)d_ws;

  // workspace layout (floats)
  float* offs = ws;                        // 64*18*4096  = 4,718,592
  float* wsd  = offs + 4718592;            // 64*16*4096  = 4,194,304
  float* ws2  = wsd + 4194304;             // 64*16*4096  = 4,194,304
  float* h2p  = ws2 + 4194304;             // 64*66*66*16 = 4,460,544
  float* stats = h2p + 4460544;            // 320
  float* sum1 = stats, *sq1 = stats + 64;
  float* sum2 = stats + 128, *sq2 = stats + 144;
  float* sum3 = stats + 160, *sq3 = stats + 176;
  float* sum4 = stats + 192, *sq4 = stats + 256;

  hipMemsetAsync(stats, 0, 320 * sizeof(float), stream);
  hipMemsetAsync(h2p, 0, 4460544 * sizeof(float), stream);

  conv1_k<<<dim3(16, 4, 64), 256, 0, stream>>>(x, w1, out);
  stats_k<<<4096, 256, 0, stream>>>(out, 64, sum1, sq1);
  conv2_k<<<1024, 256, 0, stream>>>(out, w2, sum1, sq1, g1, b1, ws2);
  stats_k<<<1024, 256, 0, stream>>>(ws2, 16, sum2, sq2);
  bnrelu2_k<<<1024, 256, 0, stream>>>(ws2, sum2, sq2, g2, b2, h2p);
  offconv_k<<<dim3(16, 64), 256, 0, stream>>>(h2p, ow, ob, offs);
  deform_k<<<1024, 256, 0, stream>>>(h2p, offs, w3, wsd);
  stats_k<<<1024, 256, 0, stream>>>(wsd, 16, sum3, sq3);
  conv4_k<<<dim3(16, 2, 64), 256, 0, stream>>>(wsd, w4, sum3, sq3, g3, b3, out);
  stats_k<<<4096, 256, 0, stream>>>(out, 64, sum4, sq4);
  final_k<<<16384, 256, 0, stream>>>(out, x, sum4, sq4, g4, b4);
}

// Round 2
// 599.823 us; speedup vs baseline: 3.7362x; 3.7362x over previous
//
#include <hip/hip_runtime.h>

// Problem constants: B=64, Cin=P=64, H=W=64, mid C=16, offsets C=18, K=3x3
// BN n = B*H*W = 262144
#define BN_N 262144.0f

typedef unsigned short u16;
typedef __attribute__((ext_vector_type(8))) short short8;   // 8 x bf16 (4 VGPRs)
typedef __attribute__((ext_vector_type(4))) float floatx4;

static __device__ __forceinline__ u16 f2bf(float f) {
  union { float f; unsigned u; } v; v.f = f;
  unsigned u = v.u;
  return (u16)((u + 0x7FFFu + ((u >> 16) & 1u)) >> 16);
}

// ---------------------------------------------------------------- prep: w1 -> frag-swizzled bf16 B matrix
// Bsw[((kc*4+kgrp)*64 + n)*8 + kin], k = tap*64+c = kc*32+kgrp*8+kin
__global__ __launch_bounds__(256) void prep_w_k(const float* __restrict__ w1,
                                                u16* __restrict__ Bsw) {
  int d = blockIdx.x * 256 + threadIdx.x;   // 0..36863
  int kin = d & 7, n = (d >> 3) & 63, kgrp = (d >> 9) & 3, kc = d >> 11;
  int k = kc * 32 + kgrp * 8 + kin;
  int tap = k >> 6, c = k & 63;
  Bsw[d] = f2bf(w1[n * 576 + c * 9 + tap]);
}

// ---------------------------------------------------------------- prep: x (NCHW fp32) -> xp padded NHWC bf16 (64,66,66,64)
__global__ __launch_bounds__(256) void prep_x_k(const float* __restrict__ x,
                                                u16* __restrict__ xp) {
  int yp = blockIdx.x;   // 0..65
  int b = blockIdx.y;
  int tid = threadIdx.x;
  u16* rowbase = xp + ((size_t)(b * 66 + yp)) * 66 * 64;
  if (yp == 0 || yp == 65) {                 // zero row: 66*64 = 4224 u16 = 1056 ushort4
    for (int i = tid; i < 1056; i += 256)
      ((ushort4*)rowbase)[i] = make_ushort4(0, 0, 0, 0);
    return;
  }
  int y = yp - 1;
  __shared__ u16 s[64][68];                  // [x][c], pad 68 for ushort4-aligned reads
  for (int i = tid; i < 4096; i += 256) {
    int c = i >> 6, xx = i & 63;
    s[xx][c] = f2bf(x[((b * 64 + c) << 12) + (y << 6) + xx]);
  }
  if (tid < 128) {                           // left/right padding columns
    int c = tid & 63;
    int xpad = (tid >> 6) ? 65 : 0;
    rowbase[xpad * 64 + c] = 0;
  }
  __syncthreads();
  for (int j = tid; j < 1024; j += 256) {
    int xx = j >> 4, c4 = (j & 15) << 2;
    *(ushort4*)(rowbase + (xx + 1) * 64 + c4) =
        make_ushort4(s[xx][c4], s[xx][c4 + 1], s[xx][c4 + 2], s[xx][c4 + 3]);
  }
}

// ---------------------------------------------------------------- conv1 as implicit GEMM, bf16 MFMA, no LDS
// M = pixels, N = 64 oc, K = 576 (tap-major, ch-minor). Wave: 32 px x 64 oc.
__global__ __launch_bounds__(256) void conv1_mfma(const u16* __restrict__ xp,
                                                  const u16* __restrict__ Bsw,
                                                  float* __restrict__ out) {
  const int tid = threadIdx.x;
  const int w = tid >> 6, l = tid & 63;
  const int b = blockIdx.y;
  const int y = (blockIdx.x << 1) + (w >> 1);    // blockIdx.x 0..31
  const int x0w = (w & 1) << 5;                  // 0 or 32
  const int lm = l & 15, lk = l >> 4;

  floatx4 acc[2][4];
#pragma unroll
  for (int mb = 0; mb < 2; ++mb)
#pragma unroll
    for (int nb = 0; nb < 4; ++nb)
      acc[mb][nb] = (floatx4){0.f, 0.f, 0.f, 0.f};

  const u16* xpb = xp + (size_t)b * 66 * 66 * 64;

#pragma unroll
  for (int kk = 0; kk < 18; ++kk) {
    const int tap = kk >> 1;
    const int dy = (tap < 3) ? 0 : ((tap < 6) ? 1 : 2);
    const int dx = tap - dy * 3;
    const int c0 = ((kk & 1) << 5) + (lk << 3);
    const u16* rowp = xpb + (((y + dy) * 66) + x0w + lm + dx) * 64 + c0;
    short8 a0 = *(const short8*)(rowp);
    short8 a1 = *(const short8*)(rowp + 16 * 64);
    const u16* bp = Bsw + (((kk * 4 + lk) * 64) + lm) * 8;
    short8 b0 = *(const short8*)(bp);
    short8 b1 = *(const short8*)(bp + 16 * 8);
    short8 b2 = *(const short8*)(bp + 32 * 8);
    short8 b3 = *(const short8*)(bp + 48 * 8);
    acc[0][0] = __builtin_amdgcn_mfma_f32_16x16x32_bf16(a0, b0, acc[0][0], 0, 0, 0);
    acc[0][1] = __builtin_amdgcn_mfma_f32_16x16x32_bf16(a0, b1, acc[0][1], 0, 0, 0);
    acc[0][2] = __builtin_amdgcn_mfma_f32_16x16x32_bf16(a0, b2, acc[0][2], 0, 0, 0);
    acc[0][3] = __builtin_amdgcn_mfma_f32_16x16x32_bf16(a0, b3, acc[0][3], 0, 0, 0);
    acc[1][0] = __builtin_amdgcn_mfma_f32_16x16x32_bf16(a1, b0, acc[1][0], 0, 0, 0);
    acc[1][1] = __builtin_amdgcn_mfma_f32_16x16x32_bf16(a1, b1, acc[1][1], 0, 0, 0);
    acc[1][2] = __builtin_amdgcn_mfma_f32_16x16x32_bf16(a1, b2, acc[1][2], 0, 0, 0);
    acc[1][3] = __builtin_amdgcn_mfma_f32_16x16x32_bf16(a1, b3, acc[1][3], 0, 0, 0);
  }

  // D-layout: oc = nb*16 + (l&15), pixel x = x0w + mb*16 + (l>>4)*4 + reg
#pragma unroll
  for (int mb = 0; mb < 2; ++mb)
#pragma unroll
    for (int nb = 0; nb < 4; ++nb) {
      float* dst = out + ((b * 64 + nb * 16 + lm) << 12) + (y << 6) + x0w + (mb << 4) + (lk << 2);
      *(floatx4*)dst = acc[mb][nb];
    }
}

// ---------------------------------------------------------------- per-channel sum/sumsq (NCHW, HW=4096)
__global__ __launch_bounds__(256) void stats_k(const float* __restrict__ src, int C,
                                               float* __restrict__ sum, float* __restrict__ sq) {
  int bi = blockIdx.x;
  int c = bi % C, b = bi / C;
  const float* p = src + (((long)b * C + c) << 12);
  float s = 0.f, s2 = 0.f;
  for (int i = threadIdx.x; i < 4096; i += 256) {
    float v = p[i];
    s += v; s2 += v * v;
  }
#pragma unroll
  for (int off = 32; off > 0; off >>= 1) {
    s += __shfl_down(s, off, 64);
    s2 += __shfl_down(s2, off, 64);
  }
  __shared__ float ls[4], ls2[4];
  int lane = threadIdx.x & 63, wv = threadIdx.x >> 6;
  if (lane == 0) { ls[wv] = s; ls2[wv] = s2; }
  __syncthreads();
  if (threadIdx.x == 0) {
    atomicAdd(&sum[c], ls[0] + ls[1] + ls[2] + ls[3]);
    atomicAdd(&sq[c],  ls2[0] + ls2[1] + ls2[2] + ls2[3]);
  }
}

// ---------------------------------------------------------------- conv2: 1x1 64->16, BN1+relu fused on input
__global__ __launch_bounds__(256) void conv2_k(const float* __restrict__ h1raw,
                                               const float* __restrict__ w2,   // (16,64)
                                               const float* __restrict__ sum1, const float* __restrict__ sq1,
                                               const float* __restrict__ g1, const float* __restrict__ b1,
                                               float* __restrict__ out) {      // raw (64,16,64,64)
  __shared__ float s_wt[64 * 16];   // transposed [c][o]
  __shared__ float s_scale[64], s_shift[64];
  int tid = threadIdx.x;
  for (int i = tid; i < 1024; i += 256) {
    int o = i >> 6, c = i & 63;
    s_wt[c * 16 + o] = w2[i];
  }
  if (tid < 64) {
    float m = sum1[tid] / BN_N;
    float var = sq1[tid] / BN_N - m * m;
    float sc = g1[tid] * rsqrtf(var + 1e-5f);
    s_scale[tid] = sc;
    s_shift[tid] = b1[tid] - m * sc;
  }
  __syncthreads();
  int p = blockIdx.x * 256 + tid;
  int b = p >> 12, r = p & 4095;
  const float* src = h1raw + (b << 18) + r;
  float acc[16];
#pragma unroll
  for (int o = 0; o < 16; ++o) acc[o] = 0.f;
  for (int c = 0; c < 64; ++c) {
    float v = src[c << 12];
    v = fmaxf(v * s_scale[c] + s_shift[c], 0.f);
    const float* wp = &s_wt[c * 16];
    float4 w0 = *(const float4*)wp;
    float4 w1 = *(const float4*)(wp + 4);
    float4 w2v = *(const float4*)(wp + 8);
    float4 w3v = *(const float4*)(wp + 12);
    acc[0] += w0.x * v;  acc[1] += w0.y * v;  acc[2] += w0.z * v;  acc[3] += w0.w * v;
    acc[4] += w1.x * v;  acc[5] += w1.y * v;  acc[6] += w1.z * v;  acc[7] += w1.w * v;
    acc[8] += w2v.x * v; acc[9] += w2v.y * v; acc[10] += w2v.z * v; acc[11] += w2v.w * v;
    acc[12] += w3v.x * v; acc[13] += w3v.y * v; acc[14] += w3v.z * v; acc[15] += w3v.w * v;
  }
  float* dst = out + (b << 16) + r;
#pragma unroll
  for (int o = 0; o < 16; ++o) dst[o << 12] = acc[o];
}

// ---------------------------------------------------------------- BN2+relu -> padded NHWC h2p (64,66,66,16)
__global__ __launch_bounds__(256) void bnrelu2_k(const float* __restrict__ ws2,
                                                 const float* __restrict__ sum2, const float* __restrict__ sq2,
                                                 const float* __restrict__ g2, const float* __restrict__ b2,
                                                 float* __restrict__ h2p) {
  __shared__ float s_scale[16], s_shift[16];
  int tid = threadIdx.x;
  if (tid < 16) {
    float m = sum2[tid] / BN_N;
    float var = sq2[tid] / BN_N - m * m;
    float sc = g2[tid] * rsqrtf(var + 1e-5f);
    s_scale[tid] = sc;
    s_shift[tid] = b2[tid] - m * sc;
  }
  __syncthreads();
  int p = blockIdx.x * 256 + tid;
  int b = p >> 12, r = p & 4095;
  int y = r >> 6, xx = r & 63;
  const float* src = ws2 + (b << 16) + r;
  float vals[16];
#pragma unroll
  for (int c = 0; c < 16; ++c)
    vals[c] = fmaxf(src[c << 12] * s_scale[c] + s_shift[c], 0.f);
  float* dst = h2p + (((b * 66) + y + 1) * 66 + xx + 1) * 16;
#pragma unroll
  for (int c4 = 0; c4 < 4; ++c4)
    *(float4*)(dst + c4 * 4) = make_float4(vals[c4*4], vals[c4*4+1], vals[c4*4+2], vals[c4*4+3]);
}

// ---------------------------------------------------------------- offsets conv: 3x3 16->18 on h2p (NHWC)
__global__ __launch_bounds__(256) void offconv_k(const float* __restrict__ h2p,
                                                 const float* __restrict__ ow,  // (18,16,3,3)
                                                 const float* __restrict__ ob,  // (18,)
                                                 float* __restrict__ offs) {    // (64,18,64,64)
  const int tile = blockIdx.x;
  const int ty0 = (tile >> 2) * 16, tx0 = (tile & 3) * 16;
  const int b = blockIdx.y;
  const int tid = threadIdx.x;
  __shared__ float s_in[16][324];        // [c][18x18]
  __shared__ float s_w[18 * 16 * 12];
  for (int i = tid; i < 5184; i += 256) {  // i = pix*16 + c for coalesced NHWC read
    int pix = i >> 4, c = i & 15;
    int yy = pix / 18, xxp = pix - yy * 18;
    s_in[c][pix] = h2p[(((b * 66) + ty0 + yy) * 66 + tx0 + xxp) * 16 + c];
  }
  for (int i = tid; i < 2592; i += 256) {
    int oc = i / 144, rem = i - oc * 144;
    int c = rem / 9, k = rem - c * 9;
    s_w[(oc * 16 + c) * 12 + k] = ow[i];
  }
  __syncthreads();
  int py = tid >> 4, px = tid & 15;
  float acc[18];
#pragma unroll
  for (int o = 0; o < 18; ++o) acc[o] = ob[o];
  for (int c = 0; c < 16; ++c) {
    float v[9];
#pragma unroll
    for (int ky = 0; ky < 3; ++ky)
#pragma unroll
      for (int kx = 0; kx < 3; ++kx)
        v[ky * 3 + kx] = s_in[c][(py + ky) * 18 + px + kx];
#pragma unroll
    for (int o = 0; o < 18; ++o) {
      const float* wp = &s_w[(o * 16 + c) * 12];
      float4 wa = *(const float4*)wp;
      float4 wb = *(const float4*)(wp + 4);
      float w8 = wp[8];
      acc[o] += wa.x * v[0] + wa.y * v[1] + wa.z * v[2] + wa.w * v[3]
              + wb.x * v[4] + wb.y * v[5] + wb.z * v[6] + wb.w * v[7]
              + w8 * v[8];
    }
  }
  int r = (ty0 + py) * 64 + tx0 + px;
  float* dst = offs + (long)b * 73728 + r;
#pragma unroll
  for (int o = 0; o < 18; ++o) dst[o << 12] = acc[o];
}

// ---------------------------------------------------------------- deformable conv: bilinear sample + einsum
__global__ __launch_bounds__(256) void deform_k(const float* __restrict__ h2p,
                                                const float* __restrict__ offs,
                                                const float* __restrict__ w3,   // (16,16,9)
                                                float* __restrict__ out) {      // raw (64,16,64,64)
  __shared__ float s_w[9 * 16 * 16];      // [k][c][o]
  int tid = threadIdx.x;
  for (int i = tid; i < 2304; i += 256) {
    int o = i / 144, rem = i - o * 144;
    int c = rem / 9, k = rem - c * 9;
    s_w[(k * 16 + c) * 16 + o] = w3[i];
  }
  __syncthreads();
  int p = blockIdx.x * 256 + tid;
  int b = p >> 12, r = p & 4095;
  int y = r >> 6, x = r & 63;
  const float* offp = offs + (long)b * 73728 + r;
  const float* img = h2p + (long)b * 66 * 66 * 16;
  float acc[16];
#pragma unroll
  for (int o = 0; o < 16; ++o) acc[o] = 0.f;
#pragma unroll
  for (int k = 0; k < 9; ++k) {
    float offy = offp[k << 12];
    float offx = offp[(k + 9) << 12];
    float py = (float)(y + (k / 3)) + offy;     // (y+1) + (k/3 - 1) + off
    float px = (float)(x + (k % 3)) + offx;
    py = fminf(fmaxf(py, 0.f), 65.f);
    px = fminf(fmaxf(px, 0.f), 65.f);
    float y0f = floorf(py), x0f = floorf(px);
    int y0 = (int)y0f, x0 = (int)x0f;
    int y1 = min(y0 + 1, 65), x1 = min(x0 + 1, 65);
    float wy = py - y0f, wx = px - x0f;
    float w00 = (1.f - wy) * (1.f - wx), w01 = (1.f - wy) * wx;
    float w10 = wy * (1.f - wx),         w11 = wy * wx;
    const float* p00 = img + (y0 * 66 + x0) * 16;
    const float* p01 = img + (y0 * 66 + x1) * 16;
    const float* p10 = img + (y1 * 66 + x0) * 16;
    const float* p11 = img + (y1 * 66 + x1) * 16;
    const float* wk = &s_w[k << 8];
#pragma unroll
    for (int c4 = 0; c4 < 4; ++c4) {
      float4 a = *(const float4*)(p00 + c4 * 4);
      float4 bq = *(const float4*)(p01 + c4 * 4);
      float4 cq = *(const float4*)(p10 + c4 * 4);
      float4 dq = *(const float4*)(p11 + c4 * 4);
      float s0 = a.x * w00 + bq.x * w01 + cq.x * w10 + dq.x * w11;
      float s1 = a.y * w00 + bq.y * w01 + cq.y * w10 + dq.y * w11;
      float s2 = a.z * w00 + bq.z * w01 + cq.z * w10 + dq.z * w11;
      float s3 = a.w * w00 + bq.w * w01 + cq.w * w10 + dq.w * w11;
      const float* wc0 = wk + c4 * 64;
#pragma unroll
      for (int o = 0; o < 16; ++o)
        acc[o] += wc0[o] * s0 + wc0[16 + o] * s1 + wc0[32 + o] * s2 + wc0[48 + o] * s3;
    }
  }
  float* dst = out + (b << 16) + r;
#pragma unroll
  for (int o = 0; o < 16; ++o) dst[o << 12] = acc[o];
}

// ---------------------------------------------------------------- conv4: 3x3 16->64, BN3+relu fused on input
__global__ __launch_bounds__(256) void conv4_k(const float* __restrict__ wsd,
                                               const float* __restrict__ w4,   // (64,16,3,3)
                                               const float* __restrict__ sum3, const float* __restrict__ sq3,
                                               const float* __restrict__ g3, const float* __restrict__ b3,
                                               float* __restrict__ out) {      // raw (64,64,64,64)
  __shared__ float s_in[16][324];
  __shared__ float s_w[32 * 16 * 12];
  __shared__ float s_scale[16], s_shift[16];
  int tid = threadIdx.x;
  if (tid < 16) {
    float m = sum3[tid] / BN_N;
    float var = sq3[tid] / BN_N - m * m;
    float sc = g3[tid] * rsqrtf(var + 1e-5f);
    s_scale[tid] = sc;
    s_shift[tid] = b3[tid] - m * sc;
  }
  __syncthreads();
  const int tile = blockIdx.x;
  const int ty0 = (tile >> 2) * 16, tx0 = (tile & 3) * 16;
  const int ocg = blockIdx.y;                  // 2 groups of 32
  const int b = blockIdx.z;
  for (int i = tid; i < 16 * 324; i += 256) {
    int c = i / 324, r = i - c * 324;
    int yy = r / 18, xx = r - yy * 18;
    int gy = ty0 + yy - 1, gx = tx0 + xx - 1;
    float v = 0.f;
    if ((unsigned)gy < 64u && (unsigned)gx < 64u) {
      v = wsd[((b * 16 + c) << 12) + (gy << 6) + gx];
      v = fmaxf(v * s_scale[c] + s_shift[c], 0.f);
    }
    s_in[c][r] = v;
  }
  for (int i = tid; i < 4608; i += 256) {       // 32*16*9
    int oc = i / 144, rem = i - oc * 144;
    int c = rem / 9, k = rem - c * 9;
    s_w[(oc * 16 + c) * 12 + k] = w4[ocg * 4608 + i];
  }
  __syncthreads();
  int py = tid >> 4, px = tid & 15;
  float acc[32];
#pragma unroll
  for (int o = 0; o < 32; ++o) acc[o] = 0.f;
  for (int c = 0; c < 16; ++c) {
    float v[9];
#pragma unroll
    for (int ky = 0; ky < 3; ++ky)
#pragma unroll
      for (int kx = 0; kx < 3; ++kx)
        v[ky * 3 + kx] = s_in[c][(py + ky) * 18 + px + kx];
#pragma unroll
    for (int o = 0; o < 32; ++o) {
      const float* wp = &s_w[(o * 16 + c) * 12];
      float4 wa = *(const float4*)wp;
      float4 wb = *(const float4*)(wp + 4);
      float w8 = wp[8];
      acc[o] += wa.x * v[0] + wa.y * v[1] + wa.z * v[2] + wa.w * v[3]
              + wb.x * v[4] + wb.y * v[5] + wb.z * v[6] + wb.w * v[7]
              + w8 * v[8];
    }
  }
  int oy = ty0 + py, ox = tx0 + px;
  float* dst = out + ((b * 64 + ocg * 32) << 12) + (oy << 6) + ox;
#pragma unroll
  for (int o = 0; o < 32; ++o) dst[o << 12] = acc[o];
}

// ---------------------------------------------------------------- final: BN4 + residual + relu (in-place on out)
__global__ __launch_bounds__(256) void final_k(float* __restrict__ out,
                                               const float* __restrict__ x,
                                               const float* __restrict__ sum4, const float* __restrict__ sq4,
                                               const float* __restrict__ g4, const float* __restrict__ b4) {
  __shared__ float s_scale[64], s_shift[64];
  int tid = threadIdx.x;
  if (tid < 64) {
    float m = sum4[tid] / BN_N;
    float var = sq4[tid] / BN_N - m * m;
    float sc = g4[tid] * rsqrtf(var + 1e-5f);
    s_scale[tid] = sc;
    s_shift[tid] = b4[tid] - m * sc;
  }
  __syncthreads();
  int i = (blockIdx.x * 256 + tid) * 4;
  int c = (i >> 12) & 63;
  float4 v = *(const float4*)(out + i);
  float4 xv = *(const float4*)(x + i);
  float sc = s_scale[c], sh = s_shift[c];
  v.x = fmaxf(v.x * sc + sh + xv.x, 0.f);
  v.y = fmaxf(v.y * sc + sh + xv.y, 0.f);
  v.z = fmaxf(v.z * sc + sh + xv.z, 0.f);
  v.w = fmaxf(v.w * sc + sh + xv.w, 0.f);
  *(float4*)(out + i) = v;
}

extern "C" void kernel_launch(void* const* d_in, const int* in_sizes, int n_in,
                              void* d_out, int out_size, void* d_ws, size_t ws_size,
                              hipStream_t stream) {
  const float* x  = (const float*)d_in[0];
  const float* w1 = (const float*)d_in[1];
  const float* g1 = (const float*)d_in[2];
  const float* b1 = (const float*)d_in[3];
  const float* w2 = (const float*)d_in[4];
  const float* g2 = (const float*)d_in[5];
  const float* b2 = (const float*)d_in[6];
  const float* ow = (const float*)d_in[7];
  const float* ob = (const float*)d_in[8];
  const float* w3 = (const float*)d_in[9];
  const float* g3 = (const float*)d_in[10];
  const float* b3 = (const float*)d_in[11];
  const float* w4 = (const float*)d_in[12];
  const float* g4 = (const float*)d_in[13];
  const float* b4 = (const float*)d_in[14];
  float* out = (float*)d_out;
  float* ws = (float*)d_ws;

  // workspace layout (float offsets)
  // xp (bf16, 17,842,176 u16 = 8,921,088 floats) OVERLAPS offs+wsd+ws2 head:
  //   xp is dead after conv1_mfma; offs/wsd/ws2 are written strictly later.
  float* offs = ws;                        // 64*18*4096  = 4,718,592
  float* wsd  = offs + 4718592;            // 64*16*4096  = 4,194,304
  float* ws2  = wsd + 4194304;             // 64*16*4096  = 4,194,304
  float* h2p  = ws2 + 4194304;             // 64*66*66*16 = 4,460,544
  float* stats = h2p + 4460544;            // 320
  float* sum1 = stats, *sq1 = stats + 64;
  float* sum2 = stats + 128, *sq2 = stats + 144;
  float* sum3 = stats + 160, *sq3 = stats + 176;
  float* sum4 = stats + 192, *sq4 = stats + 256;
  u16* xp  = (u16*)ws;                     // bf16 NHWC padded input
  u16* Bsw = (u16*)(stats + 320);          // 36,864 u16 swizzled conv1 weights

  hipMemsetAsync(stats, 0, 320 * sizeof(float), stream);
  hipMemsetAsync(h2p, 0, 4460544 * sizeof(float), stream);

  prep_w_k<<<144, 256, 0, stream>>>(w1, Bsw);
  prep_x_k<<<dim3(66, 64), 256, 0, stream>>>(x, xp);
  conv1_mfma<<<dim3(32, 64), 256, 0, stream>>>(xp, Bsw, out);
  stats_k<<<4096, 256, 0, stream>>>(out, 64, sum1, sq1);
  conv2_k<<<1024, 256, 0, stream>>>(out, w2, sum1, sq1, g1, b1, ws2);
  stats_k<<<1024, 256, 0, stream>>>(ws2, 16, sum2, sq2);
  bnrelu2_k<<<1024, 256, 0, stream>>>(ws2, sum2, sq2, g2, b2, h2p);
  offconv_k<<<dim3(16, 64), 256, 0, stream>>>(h2p, ow, ob, offs);
  deform_k<<<1024, 256, 0, stream>>>(h2p, offs, w3, wsd);
  stats_k<<<1024, 256, 0, stream>>>(wsd, 16, sum3, sq3);
  conv4_k<<<dim3(16, 2, 64), 256, 0, stream>>>(wsd, w4, sum3, sq3, g3, b3, out);
  stats_k<<<4096, 256, 0, stream>>>(out, 64, sum4, sq4);
  final_k<<<16384, 256, 0, stream>>>(out, x, sum4, sq4, g4, b4);
}

// Round 3
// 505.034 us; speedup vs baseline: 4.4374x; 1.1877x over previous
//
#include <hip/hip_runtime.h>

// B=64, Cin=P=64, H=W=64, mid C=16, offsets C=18, K=3x3.  BN n = 262144
#define BN_N 262144.0f

typedef unsigned short u16;
typedef __attribute__((ext_vector_type(8))) short short8;   // 8 x bf16
typedef __attribute__((ext_vector_type(4))) float floatx4;

static __device__ __forceinline__ u16 f2bf(float f) {
  union { float f; unsigned u; } v; v.f = f;
  unsigned u = v.u;
  return (u16)((u + 0x7FFFu + ((u >> 16) & 1u)) >> 16);
}
static __device__ __forceinline__ float bf2f(u16 h) {
  union { unsigned u; float f; } v; v.u = ((unsigned)h) << 16;
  return v.f;
}

// ---------------------------------------------------------------- prep: w1 -> swizzled bf16 B (conv1)
__global__ __launch_bounds__(256) void prep_w_k(const float* __restrict__ w1,
                                                u16* __restrict__ Bsw) {
  int d = blockIdx.x * 256 + threadIdx.x;   // 0..36863
  int kin = d & 7, n = (d >> 3) & 63, kgrp = (d >> 9) & 3, kc = d >> 11;
  int k = kc * 32 + kgrp * 8 + kin;
  int tap = k >> 6, c = k & 63;
  Bsw[d] = f2bf(w1[n * 576 + c * 9 + tap]);
}

// ---------------------------------------------------------------- prep: w4 -> swizzled bf16 B (conv4), K padded 144->160
__global__ __launch_bounds__(256) void prep_w4_k(const float* __restrict__ w4,
                                                 u16* __restrict__ Bsw4) {
  int d = blockIdx.x * 256 + threadIdx.x;   // 0..10239
  if (d >= 10240) return;
  int kin = d & 7, n = (d >> 3) & 63, lk = (d >> 9) & 3, kk = d >> 11;
  int tap = kk * 2 + (lk >> 1);
  int c = ((lk & 1) << 3) + kin;
  float v = (tap < 9) ? w4[n * 144 + c * 9 + tap] : 0.f;
  Bsw4[d] = f2bf(v);
}

// ---------------------------------------------------------------- prep: x -> padded NHWC bf16 (64,66,66,64)
__global__ __launch_bounds__(256) void prep_x_k(const float* __restrict__ x,
                                                u16* __restrict__ xp) {
  int yp = blockIdx.x;   // 0..65
  int b = blockIdx.y;
  int tid = threadIdx.x;
  u16* rowbase = xp + ((size_t)(b * 66 + yp)) * 66 * 64;
  if (yp == 0 || yp == 65) {
    for (int i = tid; i < 1056; i += 256)
      ((ushort4*)rowbase)[i] = make_ushort4(0, 0, 0, 0);
    return;
  }
  int y = yp - 1;
  __shared__ u16 s[64][68];
  for (int i = tid; i < 4096; i += 256) {
    int c = i >> 6, xx = i & 63;
    s[xx][c] = f2bf(x[((b * 64 + c) << 12) + (y << 6) + xx]);
  }
  if (tid < 128) {
    int c = tid & 63;
    int xpad = (tid >> 6) ? 65 : 0;
    rowbase[xpad * 64 + c] = 0;
  }
  __syncthreads();
  for (int j = tid; j < 1024; j += 256) {
    int xx = j >> 4, c4 = (j & 15) << 2;
    *(ushort4*)(rowbase + (xx + 1) * 64 + c4) =
        make_ushort4(s[xx][c4], s[xx][c4 + 1], s[xx][c4 + 2], s[xx][c4 + 3]);
  }
}

// ---------------------------------------------------------------- conv1 implicit GEMM bf16 MFMA (no LDS)
__global__ __launch_bounds__(256) void conv1_mfma(const u16* __restrict__ xp,
                                                  const u16* __restrict__ Bsw,
                                                  float* __restrict__ out) {
  const int tid = threadIdx.x;
  const int w = tid >> 6, l = tid & 63;
  const int b = blockIdx.y;
  const int y = (blockIdx.x << 1) + (w >> 1);
  const int x0w = (w & 1) << 5;
  const int lm = l & 15, lk = l >> 4;

  floatx4 acc[2][4];
#pragma unroll
  for (int mb = 0; mb < 2; ++mb)
#pragma unroll
    for (int nb = 0; nb < 4; ++nb)
      acc[mb][nb] = (floatx4){0.f, 0.f, 0.f, 0.f};

  const u16* xpb = xp + (size_t)b * 66 * 66 * 64;

#pragma unroll
  for (int kk = 0; kk < 18; ++kk) {
    const int tap = kk >> 1;
    const int dy = (tap < 3) ? 0 : ((tap < 6) ? 1 : 2);
    const int dx = tap - dy * 3;
    const int c0 = ((kk & 1) << 5) + (lk << 3);
    const u16* rowp = xpb + (((y + dy) * 66) + x0w + lm + dx) * 64 + c0;
    short8 a0 = *(const short8*)(rowp);
    short8 a1 = *(const short8*)(rowp + 16 * 64);
    const u16* bp = Bsw + (((kk * 4 + lk) * 64) + lm) * 8;
    short8 b0 = *(const short8*)(bp);
    short8 b1 = *(const short8*)(bp + 16 * 8);
    short8 b2 = *(const short8*)(bp + 32 * 8);
    short8 b3 = *(const short8*)(bp + 48 * 8);
    acc[0][0] = __builtin_amdgcn_mfma_f32_16x16x32_bf16(a0, b0, acc[0][0], 0, 0, 0);
    acc[0][1] = __builtin_amdgcn_mfma_f32_16x16x32_bf16(a0, b1, acc[0][1], 0, 0, 0);
    acc[0][2] = __builtin_amdgcn_mfma_f32_16x16x32_bf16(a0, b2, acc[0][2], 0, 0, 0);
    acc[0][3] = __builtin_amdgcn_mfma_f32_16x16x32_bf16(a0, b3, acc[0][3], 0, 0, 0);
    acc[1][0] = __builtin_amdgcn_mfma_f32_16x16x32_bf16(a1, b0, acc[1][0], 0, 0, 0);
    acc[1][1] = __builtin_amdgcn_mfma_f32_16x16x32_bf16(a1, b1, acc[1][1], 0, 0, 0);
    acc[1][2] = __builtin_amdgcn_mfma_f32_16x16x32_bf16(a1, b2, acc[1][2], 0, 0, 0);
    acc[1][3] = __builtin_amdgcn_mfma_f32_16x16x32_bf16(a1, b3, acc[1][3], 0, 0, 0);
  }

#pragma unroll
  for (int mb = 0; mb < 2; ++mb)
#pragma unroll
    for (int nb = 0; nb < 4; ++nb) {
      float* dst = out + ((b * 64 + nb * 16 + lm) << 12) + (y << 6) + x0w + (mb << 4) + (lk << 2);
      *(floatx4*)dst = acc[mb][nb];
    }
}

// ---------------------------------------------------------------- per-channel sum/sumsq fp32 NCHW
__global__ __launch_bounds__(256) void stats_k(const float* __restrict__ src, int C,
                                               float* __restrict__ sum, float* __restrict__ sq) {
  int bi = blockIdx.x;
  int c = bi % C, b = bi / C;
  const float* p = src + (((long)b * C + c) << 12);
  float s = 0.f, s2 = 0.f;
  for (int i = threadIdx.x; i < 4096; i += 256) {
    float v = p[i];
    s += v; s2 += v * v;
  }
#pragma unroll
  for (int off = 32; off > 0; off >>= 1) {
    s += __shfl_down(s, off, 64);
    s2 += __shfl_down(s2, off, 64);
  }
  __shared__ float ls[4], ls2[4];
  int lane = threadIdx.x & 63, wv = threadIdx.x >> 6;
  if (lane == 0) { ls[wv] = s; ls2[wv] = s2; }
  __syncthreads();
  if (threadIdx.x == 0) {
    atomicAdd(&sum[c], ls[0] + ls[1] + ls[2] + ls[3]);
    atomicAdd(&sq[c],  ls2[0] + ls2[1] + ls2[2] + ls2[3]);
  }
}

// ---------------------------------------------------------------- per-channel sum/sumsq bf16 NCHW (C=64)
__global__ __launch_bounds__(256) void stats_bf16_k(const u16* __restrict__ src,
                                                    float* __restrict__ sum, float* __restrict__ sq) {
  int bi = blockIdx.x;
  int c = bi & 63, b = bi >> 6;
  const ushort4* p = (const ushort4*)(src + (((long)b * 64 + c) << 12));
  float s = 0.f, s2 = 0.f;
  for (int i = threadIdx.x; i < 1024; i += 256) {
    ushort4 q = p[i];
    float v0 = bf2f(q.x), v1 = bf2f(q.y), v2 = bf2f(q.z), v3 = bf2f(q.w);
    s += v0 + v1 + v2 + v3;
    s2 += v0 * v0 + v1 * v1 + v2 * v2 + v3 * v3;
  }
#pragma unroll
  for (int off = 32; off > 0; off >>= 1) {
    s += __shfl_down(s, off, 64);
    s2 += __shfl_down(s2, off, 64);
  }
  __shared__ float ls[4], ls2[4];
  int lane = threadIdx.x & 63, wv = threadIdx.x >> 6;
  if (lane == 0) { ls[wv] = s; ls2[wv] = s2; }
  __syncthreads();
  if (threadIdx.x == 0) {
    atomicAdd(&sum[c], ls[0] + ls[1] + ls[2] + ls[3]);
    atomicAdd(&sq[c],  ls2[0] + ls2[1] + ls2[2] + ls2[3]);
  }
}

// ---------------------------------------------------------------- conv2: 1x1 64->16, BN1+relu fused, NHWC out + fused stats2
__global__ __launch_bounds__(256) void conv2_k(const float* __restrict__ h1raw,
                                               const float* __restrict__ w2,
                                               const float* __restrict__ sum1, const float* __restrict__ sq1,
                                               const float* __restrict__ g1, const float* __restrict__ b1,
                                               float* __restrict__ out,        // NHWC (64,4096,16)
                                               float* __restrict__ sum2, float* __restrict__ sq2) {
  __shared__ float s_wt[64 * 16];
  __shared__ float s_scale[64], s_shift[64];
  __shared__ float ls[4][16], lsq[4][16];
  int tid = threadIdx.x;
  for (int i = tid; i < 1024; i += 256) {
    int o = i >> 6, c = i & 63;
    s_wt[c * 16 + o] = w2[i];
  }
  if (tid < 64) {
    float m = sum1[tid] / BN_N;
    float var = sq1[tid] / BN_N - m * m;
    float sc = g1[tid] * rsqrtf(var + 1e-5f);
    s_scale[tid] = sc;
    s_shift[tid] = b1[tid] - m * sc;
  }
  __syncthreads();
  int p = blockIdx.x * 256 + tid;
  int b = p >> 12, r = p & 4095;
  const float* src = h1raw + (b << 18) + r;
  float acc[16];
#pragma unroll
  for (int o = 0; o < 16; ++o) acc[o] = 0.f;
  for (int c = 0; c < 64; ++c) {
    float v = src[c << 12];
    v = fmaxf(v * s_scale[c] + s_shift[c], 0.f);
    const float* wp = &s_wt[c * 16];
    float4 w0 = *(const float4*)wp;
    float4 w1 = *(const float4*)(wp + 4);
    float4 w2v = *(const float4*)(wp + 8);
    float4 w3v = *(const float4*)(wp + 12);
    acc[0] += w0.x * v;  acc[1] += w0.y * v;  acc[2] += w0.z * v;  acc[3] += w0.w * v;
    acc[4] += w1.x * v;  acc[5] += w1.y * v;  acc[6] += w1.z * v;  acc[7] += w1.w * v;
    acc[8] += w2v.x * v; acc[9] += w2v.y * v; acc[10] += w2v.z * v; acc[11] += w2v.w * v;
    acc[12] += w3v.x * v; acc[13] += w3v.y * v; acc[14] += w3v.z * v; acc[15] += w3v.w * v;
  }
  float* dst = out + (size_t)p * 16;
#pragma unroll
  for (int c4 = 0; c4 < 4; ++c4)
    *(float4*)(dst + c4 * 4) = make_float4(acc[c4*4], acc[c4*4+1], acc[c4*4+2], acc[c4*4+3]);
  // fused stats
  int lane = tid & 63, wv = tid >> 6;
#pragma unroll
  for (int o = 0; o < 16; ++o) {
    float s = acc[o], s2 = acc[o] * acc[o];
#pragma unroll
    for (int off = 32; off > 0; off >>= 1) {
      s += __shfl_down(s, off, 64);
      s2 += __shfl_down(s2, off, 64);
    }
    if (lane == 0) { ls[wv][o] = s; lsq[wv][o] = s2; }
  }
  __syncthreads();
  if (tid < 16) atomicAdd(&sum2[tid], ls[0][tid] + ls[1][tid] + ls[2][tid] + ls[3][tid]);
  else if (tid < 32) {
    int o = tid - 16;
    atomicAdd(&sq2[o], lsq[0][o] + lsq[1][o] + lsq[2][o] + lsq[3][o]);
  }
}

// ---------------------------------------------------------------- BN2+relu: NHWC -> padded NHWC fp32 h2p
__global__ __launch_bounds__(256) void bnrelu2_k(const float* __restrict__ ws2,
                                                 const float* __restrict__ sum2, const float* __restrict__ sq2,
                                                 const float* __restrict__ g2, const float* __restrict__ b2,
                                                 float* __restrict__ h2p) {
  __shared__ float s_scale[16], s_shift[16];
  int tid = threadIdx.x;
  if (tid < 16) {
    float m = sum2[tid] / BN_N;
    float var = sq2[tid] / BN_N - m * m;
    float sc = g2[tid] * rsqrtf(var + 1e-5f);
    s_scale[tid] = sc;
    s_shift[tid] = b2[tid] - m * sc;
  }
  __syncthreads();
  int p = blockIdx.x * 256 + tid;
  int b = p >> 12, r = p & 4095;
  int y = r >> 6, xx = r & 63;
  const float* src = ws2 + (size_t)p * 16;
  float* dst = h2p + (((b * 66) + y + 1) * 66 + xx + 1) * 16;
#pragma unroll
  for (int c4 = 0; c4 < 4; ++c4) {
    float4 v = *(const float4*)(src + c4 * 4);
    v.x = fmaxf(v.x * s_scale[c4*4]   + s_shift[c4*4],   0.f);
    v.y = fmaxf(v.y * s_scale[c4*4+1] + s_shift[c4*4+1], 0.f);
    v.z = fmaxf(v.z * s_scale[c4*4+2] + s_shift[c4*4+2], 0.f);
    v.w = fmaxf(v.w * s_scale[c4*4+3] + s_shift[c4*4+3], 0.f);
    *(float4*)(dst + c4 * 4) = v;
  }
}

// ---------------------------------------------------------------- offsets conv: 3x3 16->18 on h2p (NHWC)
__global__ __launch_bounds__(256) void offconv_k(const float* __restrict__ h2p,
                                                 const float* __restrict__ ow,
                                                 const float* __restrict__ ob,
                                                 float* __restrict__ offs) {    // (64,18,64,64)
  const int tile = blockIdx.x;
  const int ty0 = (tile >> 2) * 16, tx0 = (tile & 3) * 16;
  const int b = blockIdx.y;
  const int tid = threadIdx.x;
  __shared__ float s_in[16][324];
  __shared__ float s_w[18 * 16 * 12];
  for (int i = tid; i < 5184; i += 256) {
    int pix = i >> 4, c = i & 15;
    int yy = pix / 18, xxp = pix - yy * 18;
    s_in[c][pix] = h2p[(((b * 66) + ty0 + yy) * 66 + tx0 + xxp) * 16 + c];
  }
  for (int i = tid; i < 2592; i += 256) {
    int oc = i / 144, rem = i - oc * 144;
    int c = rem / 9, k = rem - c * 9;
    s_w[(oc * 16 + c) * 12 + k] = ow[i];
  }
  __syncthreads();
  int py = tid >> 4, px = tid & 15;
  float acc[18];
#pragma unroll
  for (int o = 0; o < 18; ++o) acc[o] = ob[o];
  for (int c = 0; c < 16; ++c) {
    float v[9];
#pragma unroll
    for (int ky = 0; ky < 3; ++ky)
#pragma unroll
      for (int kx = 0; kx < 3; ++kx)
        v[ky * 3 + kx] = s_in[c][(py + ky) * 18 + px + kx];
#pragma unroll
    for (int o = 0; o < 18; ++o) {
      const float* wp = &s_w[(o * 16 + c) * 12];
      float4 wa = *(const float4*)wp;
      float4 wb = *(const float4*)(wp + 4);
      float w8 = wp[8];
      acc[o] += wa.x * v[0] + wa.y * v[1] + wa.z * v[2] + wa.w * v[3]
              + wb.x * v[4] + wb.y * v[5] + wb.z * v[6] + wb.w * v[7]
              + w8 * v[8];
    }
  }
  int r = (ty0 + py) * 64 + tx0 + px;
  float* dst = offs + (long)b * 73728 + r;
#pragma unroll
  for (int o = 0; o < 18; ++o) dst[o << 12] = acc[o];
}

// ---------------------------------------------------------------- deformable conv: NHWC out + fused stats3
__global__ __launch_bounds__(256) void deform_k(const float* __restrict__ h2p,
                                                const float* __restrict__ offs,
                                                const float* __restrict__ w3,
                                                float* __restrict__ out,        // NHWC (64,4096,16)
                                                float* __restrict__ sum3, float* __restrict__ sq3) {
  __shared__ float s_w[9 * 16 * 16];      // [k][c][o]
  __shared__ float ls[4][16], lsq[4][16];
  int tid = threadIdx.x;
  for (int i = tid; i < 2304; i += 256) {
    int o = i / 144, rem = i - o * 144;
    int c = rem / 9, k = rem - c * 9;
    s_w[(k * 16 + c) * 16 + o] = w3[i];
  }
  __syncthreads();
  int p = blockIdx.x * 256 + tid;
  int b = p >> 12, r = p & 4095;
  int y = r >> 6, x = r & 63;
  const float* offp = offs + (long)b * 73728 + r;
  const float* img = h2p + (long)b * 66 * 66 * 16;
  float acc[16];
#pragma unroll
  for (int o = 0; o < 16; ++o) acc[o] = 0.f;
#pragma unroll
  for (int k = 0; k < 9; ++k) {
    float offy = offp[k << 12];
    float offx = offp[(k + 9) << 12];
    float py = (float)(y + (k / 3)) + offy;
    float px = (float)(x + (k % 3)) + offx;
    py = fminf(fmaxf(py, 0.f), 65.f);
    px = fminf(fmaxf(px, 0.f), 65.f);
    float y0f = floorf(py), x0f = floorf(px);
    int y0 = (int)y0f, x0 = (int)x0f;
    int y1 = min(y0 + 1, 65), x1 = min(x0 + 1, 65);
    float wy = py - y0f, wx = px - x0f;
    float w00 = (1.f - wy) * (1.f - wx), w01 = (1.f - wy) * wx;
    float w10 = wy * (1.f - wx),         w11 = wy * wx;
    const float* p00 = img + (y0 * 66 + x0) * 16;
    const float* p01 = img + (y0 * 66 + x1) * 16;
    const float* p10 = img + (y1 * 66 + x0) * 16;
    const float* p11 = img + (y1 * 66 + x1) * 16;
    const float* wk = &s_w[k << 8];
#pragma unroll
    for (int c4 = 0; c4 < 4; ++c4) {
      float4 a = *(const float4*)(p00 + c4 * 4);
      float4 bq = *(const float4*)(p01 + c4 * 4);
      float4 cq = *(const float4*)(p10 + c4 * 4);
      float4 dq = *(const float4*)(p11 + c4 * 4);
      float s0 = a.x * w00 + bq.x * w01 + cq.x * w10 + dq.x * w11;
      float s1 = a.y * w00 + bq.y * w01 + cq.y * w10 + dq.y * w11;
      float s2 = a.z * w00 + bq.z * w01 + cq.z * w10 + dq.z * w11;
      float s3 = a.w * w00 + bq.w * w01 + cq.w * w10 + dq.w * w11;
      const float* wc0 = wk + c4 * 64;
#pragma unroll
      for (int o = 0; o < 16; ++o)
        acc[o] += wc0[o] * s0 + wc0[16 + o] * s1 + wc0[32 + o] * s2 + wc0[48 + o] * s3;
    }
  }
  float* dst = out + (size_t)p * 16;
#pragma unroll
  for (int c4 = 0; c4 < 4; ++c4)
    *(float4*)(dst + c4 * 4) = make_float4(acc[c4*4], acc[c4*4+1], acc[c4*4+2], acc[c4*4+3]);
  // fused stats
  int lane = tid & 63, wv = tid >> 6;
#pragma unroll
  for (int o = 0; o < 16; ++o) {
    float s = acc[o], s2 = acc[o] * acc[o];
#pragma unroll
    for (int off = 32; off > 0; off >>= 1) {
      s += __shfl_down(s, off, 64);
      s2 += __shfl_down(s2, off, 64);
    }
    if (lane == 0) { ls[wv][o] = s; lsq[wv][o] = s2; }
  }
  __syncthreads();
  if (tid < 16) atomicAdd(&sum3[tid], ls[0][tid] + ls[1][tid] + ls[2][tid] + ls[3][tid]);
  else if (tid < 32) {
    int o = tid - 16;
    atomicAdd(&sq3[o], lsq[0][o] + lsq[1][o] + lsq[2][o] + lsq[3][o]);
  }
}

// ---------------------------------------------------------------- BN3+relu: NHWC fp32 -> padded NHWC bf16 h3p
__global__ __launch_bounds__(256) void bnrelu3_k(const float* __restrict__ wsd,
                                                 const float* __restrict__ sum3, const float* __restrict__ sq3,
                                                 const float* __restrict__ g3, const float* __restrict__ b3,
                                                 u16* __restrict__ h3p) {
  __shared__ float s_scale[16], s_shift[16];
  int tid = threadIdx.x;
  if (tid < 16) {
    float m = sum3[tid] / BN_N;
    float var = sq3[tid] / BN_N - m * m;
    float sc = g3[tid] * rsqrtf(var + 1e-5f);
    s_scale[tid] = sc;
    s_shift[tid] = b3[tid] - m * sc;
  }
  __syncthreads();
  int p = blockIdx.x * 256 + tid;
  int b = p >> 12, r = p & 4095;
  int y = r >> 6, xx = r & 63;
  const float* src = wsd + (size_t)p * 16;
  u16* dst = h3p + (size_t)(((b * 66) + y + 1) * 66 + xx + 1) * 16;
#pragma unroll
  for (int c4 = 0; c4 < 4; ++c4) {
    float4 v = *(const float4*)(src + c4 * 4);
    u16 o0 = f2bf(fmaxf(v.x * s_scale[c4*4]   + s_shift[c4*4],   0.f));
    u16 o1 = f2bf(fmaxf(v.y * s_scale[c4*4+1] + s_shift[c4*4+1], 0.f));
    u16 o2 = f2bf(fmaxf(v.z * s_scale[c4*4+2] + s_shift[c4*4+2], 0.f));
    u16 o3 = f2bf(fmaxf(v.w * s_scale[c4*4+3] + s_shift[c4*4+3], 0.f));
    *(ushort4*)(dst + c4 * 4) = make_ushort4(o0, o1, o2, o3);
  }
}

// ---------------------------------------------------------------- conv4 implicit GEMM bf16 MFMA, K=144 (pad 160)
__global__ __launch_bounds__(256) void conv4_mfma(const u16* __restrict__ h3p,
                                                  const u16* __restrict__ Bsw4,
                                                  u16* __restrict__ h4) {   // bf16 NCHW raw
  const int tid = threadIdx.x;
  const int w = tid >> 6, l = tid & 63;
  const int b = blockIdx.y;
  const int y = (blockIdx.x << 1) + (w >> 1);
  const int x0w = (w & 1) << 5;
  const int lm = l & 15, lk = l >> 4;

  floatx4 acc[2][4];
#pragma unroll
  for (int mb = 0; mb < 2; ++mb)
#pragma unroll
    for (int nb = 0; nb < 4; ++nb)
      acc[mb][nb] = (floatx4){0.f, 0.f, 0.f, 0.f};

  const u16* hb = h3p + (size_t)b * 66 * 66 * 16;

#pragma unroll
  for (int kk = 0; kk < 5; ++kk) {
    int tap = kk * 2 + (lk >> 1);
    if (tap > 8) tap = 8;                     // pad lanes: B is zero there
    const int dy = tap / 3, dx = tap - dy * 3;
    const int c0 = (lk & 1) << 3;
    const u16* rowp = hb + (size_t)(((y + dy) * 66) + x0w + lm + dx) * 16 + c0;
    short8 a0 = *(const short8*)(rowp);
    short8 a1 = *(const short8*)(rowp + 16 * 16);
    const u16* bp = Bsw4 + (((kk * 4 + lk) * 64) + lm) * 8;
    short8 b0 = *(const short8*)(bp);
    short8 b1 = *(const short8*)(bp + 16 * 8);
    short8 b2 = *(const short8*)(bp + 32 * 8);
    short8 b3 = *(const short8*)(bp + 48 * 8);
    acc[0][0] = __builtin_amdgcn_mfma_f32_16x16x32_bf16(a0, b0, acc[0][0], 0, 0, 0);
    acc[0][1] = __builtin_amdgcn_mfma_f32_16x16x32_bf16(a0, b1, acc[0][1], 0, 0, 0);
    acc[0][2] = __builtin_amdgcn_mfma_f32_16x16x32_bf16(a0, b2, acc[0][2], 0, 0, 0);
    acc[0][3] = __builtin_amdgcn_mfma_f32_16x16x32_bf16(a0, b3, acc[0][3], 0, 0, 0);
    acc[1][0] = __builtin_amdgcn_mfma_f32_16x16x32_bf16(a1, b0, acc[1][0], 0, 0, 0);
    acc[1][1] = __builtin_amdgcn_mfma_f32_16x16x32_bf16(a1, b1, acc[1][1], 0, 0, 0);
    acc[1][2] = __builtin_amdgcn_mfma_f32_16x16x32_bf16(a1, b2, acc[1][2], 0, 0, 0);
    acc[1][3] = __builtin_amdgcn_mfma_f32_16x16x32_bf16(a1, b3, acc[1][3], 0, 0, 0);
  }

#pragma unroll
  for (int mb = 0; mb < 2; ++mb)
#pragma unroll
    for (int nb = 0; nb < 4; ++nb) {
      u16* dst = h4 + ((size_t)(b * 64 + nb * 16 + lm) << 12) + (y << 6) + x0w + (mb << 4) + (lk << 2);
      floatx4 v = acc[mb][nb];
      *(ushort4*)dst = make_ushort4(f2bf(v.x), f2bf(v.y), f2bf(v.z), f2bf(v.w));
    }
}

// ---------------------------------------------------------------- final: BN4 + residual + relu (h4 bf16 -> out fp32)
__global__ __launch_bounds__(256) void final_k(const u16* __restrict__ h4,
                                               float* __restrict__ out,
                                               const float* __restrict__ x,
                                               const float* __restrict__ sum4, const float* __restrict__ sq4,
                                               const float* __restrict__ g4, const float* __restrict__ b4) {
  __shared__ float s_scale[64], s_shift[64];
  int tid = threadIdx.x;
  if (tid < 64) {
    float m = sum4[tid] / BN_N;
    float var = sq4[tid] / BN_N - m * m;
    float sc = g4[tid] * rsqrtf(var + 1e-5f);
    s_scale[tid] = sc;
    s_shift[tid] = b4[tid] - m * sc;
  }
  __syncthreads();
  int i = (blockIdx.x * 256 + tid) * 4;
  int c = (i >> 12) & 63;
  ushort4 q = *(const ushort4*)(h4 + i);
  float4 xv = *(const float4*)(x + i);
  float sc = s_scale[c], sh = s_shift[c];
  float4 v;
  v.x = fmaxf(bf2f(q.x) * sc + sh + xv.x, 0.f);
  v.y = fmaxf(bf2f(q.y) * sc + sh + xv.y, 0.f);
  v.z = fmaxf(bf2f(q.z) * sc + sh + xv.z, 0.f);
  v.w = fmaxf(bf2f(q.w) * sc + sh + xv.w, 0.f);
  *(float4*)(out + i) = v;
}

extern "C" void kernel_launch(void* const* d_in, const int* in_sizes, int n_in,
                              void* d_out, int out_size, void* d_ws, size_t ws_size,
                              hipStream_t stream) {
  const float* x  = (const float*)d_in[0];
  const float* w1 = (const float*)d_in[1];
  const float* g1 = (const float*)d_in[2];
  const float* b1 = (const float*)d_in[3];
  const float* w2 = (const float*)d_in[4];
  const float* g2 = (const float*)d_in[5];
  const float* b2 = (const float*)d_in[6];
  const float* ow = (const float*)d_in[7];
  const float* ob = (const float*)d_in[8];
  const float* w3 = (const float*)d_in[9];
  const float* g3 = (const float*)d_in[10];
  const float* b3 = (const float*)d_in[11];
  const float* w4 = (const float*)d_in[12];
  const float* g4 = (const float*)d_in[13];
  const float* b4 = (const float*)d_in[14];
  float* out = (float*)d_out;
  float* ws = (float*)d_ws;

  // workspace layout (float offsets):
  //   offs  (64,18,4096)            4,718,592   dead after deform_k -> h4 overlays
  //   wsd   NHWC (64,4096,16)       4,194,304
  //   ws2   NHWC (64,4096,16)       4,194,304
  //   h2p   padded NHWC fp32        4,460,544   dead after deform_k -> h3p overlays
  //   stats                         320
  //   Bsw / Bsw4 (u16)              36,864 + 10,240
  // xp (bf16 input, 8,921,088 floats) overlays offs+wsd+ws2-head; dead after conv1.
  float* offs = ws;
  float* wsd  = offs + 4718592;
  float* ws2  = wsd + 4194304;
  float* h2p  = ws2 + 4194304;
  float* stats = h2p + 4460544;
  float* sum1 = stats, *sq1 = stats + 64;
  float* sum2 = stats + 128, *sq2 = stats + 144;
  float* sum3 = stats + 160, *sq3 = stats + 176;
  float* sum4 = stats + 192, *sq4 = stats + 256;
  u16* xp   = (u16*)ws;
  u16* Bsw  = (u16*)(stats + 320);
  u16* Bsw4 = Bsw + 36864;
  u16* h3p  = (u16*)h2p;     // bf16 padded NHWC (64,66,66,16), overlays dead h2p
  u16* h4   = (u16*)offs;    // bf16 NCHW conv4 raw, overlays dead offs

  hipMemsetAsync(stats, 0, 320 * sizeof(float), stream);
  hipMemsetAsync(h2p, 0, 4460544 * sizeof(float), stream);

  prep_w_k<<<144, 256, 0, stream>>>(w1, Bsw);
  prep_w4_k<<<40, 256, 0, stream>>>(w4, Bsw4);
  prep_x_k<<<dim3(66, 64), 256, 0, stream>>>(x, xp);
  conv1_mfma<<<dim3(32, 64), 256, 0, stream>>>(xp, Bsw, out);
  stats_k<<<4096, 256, 0, stream>>>(out, 64, sum1, sq1);
  conv2_k<<<1024, 256, 0, stream>>>(out, w2, sum1, sq1, g1, b1, ws2, sum2, sq2);
  bnrelu2_k<<<1024, 256, 0, stream>>>(ws2, sum2, sq2, g2, b2, h2p);
  offconv_k<<<dim3(16, 64), 256, 0, stream>>>(h2p, ow, ob, offs);
  deform_k<<<1024, 256, 0, stream>>>(h2p, offs, w3, wsd, sum3, sq3);
  hipMemsetAsync(h3p, 0, 4460544 * sizeof(u16), stream);   // borders for padded bf16
  bnrelu3_k<<<1024, 256, 0, stream>>>(wsd, sum3, sq3, g3, b3, h3p);
  conv4_mfma<<<dim3(32, 64), 256, 0, stream>>>(h3p, Bsw4, h4);
  stats_bf16_k<<<4096, 256, 0, stream>>>(h4, sum4, sq4);
  final_k<<<16384, 256, 0, stream>>>(h4, out, x, sum4, sq4, g4, b4);
}

// Round 4
// 397.430 us; speedup vs baseline: 5.6388x; 1.2708x over previous
//
#include <hip/hip_runtime.h>

// B=64, Cin=P=64, H=W=64, mid C=16, offsets C=18, K=3x3.  BN n = 262144
#define BN_N 262144.0f

typedef unsigned short u16;
typedef __attribute__((ext_vector_type(8))) short short8;   // 8 x bf16
typedef __attribute__((ext_vector_type(4))) float floatx4;

static __device__ __forceinline__ u16 f2bf(float f) {
  union { float f; unsigned u; } v; v.f = f;
  unsigned u = v.u;
  return (u16)((u + 0x7FFFu + ((u >> 16) & 1u)) >> 16);
}
static __device__ __forceinline__ float bf2f(u16 h) {
  union { unsigned u; float f; } v; v.u = ((unsigned)h) << 16;
  return v.f;
}

// ---------------------------------------------------------------- prep: w1 -> swizzled bf16 B (conv1, K=576)
__global__ __launch_bounds__(256) void prep_w_k(const float* __restrict__ w1,
                                                u16* __restrict__ Bsw) {
  int d = blockIdx.x * 256 + threadIdx.x;   // 0..36863
  int kin = d & 7, n = (d >> 3) & 63, kgrp = (d >> 9) & 3, kc = d >> 11;
  int k = kc * 32 + kgrp * 8 + kin;
  int tap = k >> 6, c = k & 63;
  Bsw[d] = f2bf(w1[n * 576 + c * 9 + tap]);
}

// ---------------------------------------------------------------- prep: w4 -> swizzled bf16 B (conv4, K=144->160)
__global__ __launch_bounds__(256) void prep_w4_k(const float* __restrict__ w4,
                                                 u16* __restrict__ Bsw4) {
  int d = blockIdx.x * 256 + threadIdx.x;   // 0..10239
  if (d >= 10240) return;
  int kin = d & 7, n = (d >> 3) & 63, lk = (d >> 9) & 3, kk = d >> 11;
  int tap = kk * 2 + (lk >> 1);
  int c = ((lk & 1) << 3) + kin;
  float v = (tap < 9) ? w4[n * 144 + c * 9 + tap] : 0.f;
  Bsw4[d] = f2bf(v);
}

// ---------------------------------------------------------------- prep: w3 -> swizzled bf16 B (deform, k=tap*16+c, K=144->160, N=16)
__global__ __launch_bounds__(256) void prep_w3_k(const float* __restrict__ w3,
                                                 u16* __restrict__ Bsw3) {
  int d = blockIdx.x * 256 + threadIdx.x;   // 0..2559
  if (d >= 2560) return;
  int kin = d & 7, n = (d >> 3) & 15, lk = (d >> 7) & 3, kk = d >> 9;
  int k = kk * 32 + lk * 8 + kin;
  int tap = k >> 4, c = k & 15;
  float v = (tap < 9) ? w3[n * 144 + c * 9 + tap] : 0.f;
  Bsw3[d] = f2bf(v);
}

// ---------------------------------------------------------------- prep: ow -> swizzled bf16 B (offconv, K=144->160, N=18->32)
__global__ __launch_bounds__(256) void prep_wo_k(const float* __restrict__ ow,
                                                 u16* __restrict__ BswO) {
  int d = blockIdx.x * 256 + threadIdx.x;   // 0..5119
  if (d >= 5120) return;
  int kin = d & 7, n = (d >> 3) & 31, lk = (d >> 8) & 3, kk = d >> 10;
  int tap = kk * 2 + (lk >> 1);
  int c = ((lk & 1) << 3) + kin;
  float v = (tap < 9 && n < 18) ? ow[n * 144 + c * 9 + tap] : 0.f;
  BswO[d] = f2bf(v);
}

// ---------------------------------------------------------------- prep: x -> padded NHWC bf16 (64,66,66,64)
__global__ __launch_bounds__(256) void prep_x_k(const float* __restrict__ x,
                                                u16* __restrict__ xp) {
  int yp = blockIdx.x;   // 0..65
  int b = blockIdx.y;
  int tid = threadIdx.x;
  u16* rowbase = xp + ((size_t)(b * 66 + yp)) * 66 * 64;
  if (yp == 0 || yp == 65) {
    for (int i = tid; i < 1056; i += 256)
      ((ushort4*)rowbase)[i] = make_ushort4(0, 0, 0, 0);
    return;
  }
  int y = yp - 1;
  __shared__ u16 s[64][68];
  for (int i = tid; i < 4096; i += 256) {
    int c = i >> 6, xx = i & 63;
    s[xx][c] = f2bf(x[((b * 64 + c) << 12) + (y << 6) + xx]);
  }
  if (tid < 128) {
    int c = tid & 63;
    int xpad = (tid >> 6) ? 65 : 0;
    rowbase[xpad * 64 + c] = 0;
  }
  __syncthreads();
  for (int j = tid; j < 1024; j += 256) {
    int xx = j >> 4, c4 = (j & 15) << 2;
    *(ushort4*)(rowbase + (xx + 1) * 64 + c4) =
        make_ushort4(s[xx][c4], s[xx][c4 + 1], s[xx][c4 + 2], s[xx][c4 + 3]);
  }
}

// ---------------------------------------------------------------- conv1 implicit GEMM bf16 MFMA + fused stats1
__global__ __launch_bounds__(256) void conv1_mfma(const u16* __restrict__ xp,
                                                  const u16* __restrict__ Bsw,
                                                  float* __restrict__ out,
                                                  float* __restrict__ sum1, float* __restrict__ sq1) {
  const int tid = threadIdx.x;
  const int w = tid >> 6, l = tid & 63;
  const int b = blockIdx.y;
  const int y = (blockIdx.x << 1) + (w >> 1);
  const int x0w = (w & 1) << 5;
  const int lm = l & 15, lk = l >> 4;

  floatx4 acc[2][4];
#pragma unroll
  for (int mb = 0; mb < 2; ++mb)
#pragma unroll
    for (int nb = 0; nb < 4; ++nb)
      acc[mb][nb] = (floatx4){0.f, 0.f, 0.f, 0.f};

  const u16* xpb = xp + (size_t)b * 66 * 66 * 64;

#pragma unroll
  for (int kk = 0; kk < 18; ++kk) {
    const int tap = kk >> 1;
    const int dy = (tap < 3) ? 0 : ((tap < 6) ? 1 : 2);
    const int dx = tap - dy * 3;
    const int c0 = ((kk & 1) << 5) + (lk << 3);
    const u16* rowp = xpb + (((y + dy) * 66) + x0w + lm + dx) * 64 + c0;
    short8 a0 = *(const short8*)(rowp);
    short8 a1 = *(const short8*)(rowp + 16 * 64);
    const u16* bp = Bsw + (((kk * 4 + lk) * 64) + lm) * 8;
    short8 b0 = *(const short8*)(bp);
    short8 b1 = *(const short8*)(bp + 16 * 8);
    short8 b2 = *(const short8*)(bp + 32 * 8);
    short8 b3 = *(const short8*)(bp + 48 * 8);
    acc[0][0] = __builtin_amdgcn_mfma_f32_16x16x32_bf16(a0, b0, acc[0][0], 0, 0, 0);
    acc[0][1] = __builtin_amdgcn_mfma_f32_16x16x32_bf16(a0, b1, acc[0][1], 0, 0, 0);
    acc[0][2] = __builtin_amdgcn_mfma_f32_16x16x32_bf16(a0, b2, acc[0][2], 0, 0, 0);
    acc[0][3] = __builtin_amdgcn_mfma_f32_16x16x32_bf16(a0, b3, acc[0][3], 0, 0, 0);
    acc[1][0] = __builtin_amdgcn_mfma_f32_16x16x32_bf16(a1, b0, acc[1][0], 0, 0, 0);
    acc[1][1] = __builtin_amdgcn_mfma_f32_16x16x32_bf16(a1, b1, acc[1][1], 0, 0, 0);
    acc[1][2] = __builtin_amdgcn_mfma_f32_16x16x32_bf16(a1, b2, acc[1][2], 0, 0, 0);
    acc[1][3] = __builtin_amdgcn_mfma_f32_16x16x32_bf16(a1, b3, acc[1][3], 0, 0, 0);
  }

#pragma unroll
  for (int mb = 0; mb < 2; ++mb)
#pragma unroll
    for (int nb = 0; nb < 4; ++nb) {
      float* dst = out + ((b * 64 + nb * 16 + lm) << 12) + (y << 6) + x0w + (mb << 4) + (lk << 2);
      *(floatx4*)dst = acc[mb][nb];
    }

  // fused stats1: lane's oc = nb*16+lm over 8 pixels
  __shared__ float lsum[4][64], lsq[4][64];
  float s[4], s2[4];
#pragma unroll
  for (int nb = 0; nb < 4; ++nb) {
    s[nb] = 0.f; s2[nb] = 0.f;
#pragma unroll
    for (int mb = 0; mb < 2; ++mb) {
      floatx4 a = acc[mb][nb];
      s[nb] += a.x + a.y + a.z + a.w;
      s2[nb] += a.x * a.x + a.y * a.y + a.z * a.z + a.w * a.w;
    }
    s[nb] += __shfl_xor(s[nb], 16, 64);  s[nb] += __shfl_xor(s[nb], 32, 64);
    s2[nb] += __shfl_xor(s2[nb], 16, 64); s2[nb] += __shfl_xor(s2[nb], 32, 64);
  }
  if (lk == 0) {
#pragma unroll
    for (int nb = 0; nb < 4; ++nb) { lsum[w][nb * 16 + lm] = s[nb]; lsq[w][nb * 16 + lm] = s2[nb]; }
  }
  __syncthreads();
  if (tid < 64) atomicAdd(&sum1[tid], lsum[0][tid] + lsum[1][tid] + lsum[2][tid] + lsum[3][tid]);
  else if (tid < 128) { int o = tid - 64; atomicAdd(&sq1[o], lsq[0][o] + lsq[1][o] + lsq[2][o] + lsq[3][o]); }
}

// ---------------------------------------------------------------- conv2: 1x1 64->16, BN1+relu fused, NHWC out + fused stats2
__global__ __launch_bounds__(256) void conv2_k(const float* __restrict__ h1raw,
                                               const float* __restrict__ w2,
                                               const float* __restrict__ sum1, const float* __restrict__ sq1,
                                               const float* __restrict__ g1, const float* __restrict__ b1,
                                               float* __restrict__ out,        // NHWC (64,4096,16)
                                               float* __restrict__ sum2, float* __restrict__ sq2) {
  __shared__ float s_wt[64 * 16];
  __shared__ float s_scale[64], s_shift[64];
  __shared__ float ls[4][16], lsq[4][16];
  int tid = threadIdx.x;
  for (int i = tid; i < 1024; i += 256) {
    int o = i >> 6, c = i & 63;
    s_wt[c * 16 + o] = w2[i];
  }
  if (tid < 64) {
    float m = sum1[tid] / BN_N;
    float var = sq1[tid] / BN_N - m * m;
    float sc = g1[tid] * rsqrtf(var + 1e-5f);
    s_scale[tid] = sc;
    s_shift[tid] = b1[tid] - m * sc;
  }
  __syncthreads();
  int p = blockIdx.x * 256 + tid;
  int b = p >> 12, r = p & 4095;
  const float* src = h1raw + (b << 18) + r;
  float acc[16];
#pragma unroll
  for (int o = 0; o < 16; ++o) acc[o] = 0.f;
  for (int c = 0; c < 64; ++c) {
    float v = src[c << 12];
    v = fmaxf(v * s_scale[c] + s_shift[c], 0.f);
    const float* wp = &s_wt[c * 16];
    float4 w0 = *(const float4*)wp;
    float4 w1 = *(const float4*)(wp + 4);
    float4 w2v = *(const float4*)(wp + 8);
    float4 w3v = *(const float4*)(wp + 12);
    acc[0] += w0.x * v;  acc[1] += w0.y * v;  acc[2] += w0.z * v;  acc[3] += w0.w * v;
    acc[4] += w1.x * v;  acc[5] += w1.y * v;  acc[6] += w1.z * v;  acc[7] += w1.w * v;
    acc[8] += w2v.x * v; acc[9] += w2v.y * v; acc[10] += w2v.z * v; acc[11] += w2v.w * v;
    acc[12] += w3v.x * v; acc[13] += w3v.y * v; acc[14] += w3v.z * v; acc[15] += w3v.w * v;
  }
  float* dst = out + (size_t)p * 16;
#pragma unroll
  for (int c4 = 0; c4 < 4; ++c4)
    *(float4*)(dst + c4 * 4) = make_float4(acc[c4*4], acc[c4*4+1], acc[c4*4+2], acc[c4*4+3]);
  int lane = tid & 63, wv = tid >> 6;
#pragma unroll
  for (int o = 0; o < 16; ++o) {
    float s = acc[o], s2 = acc[o] * acc[o];
#pragma unroll
    for (int off = 32; off > 0; off >>= 1) {
      s += __shfl_down(s, off, 64);
      s2 += __shfl_down(s2, off, 64);
    }
    if (lane == 0) { ls[wv][o] = s; lsq[wv][o] = s2; }
  }
  __syncthreads();
  if (tid < 16) atomicAdd(&sum2[tid], ls[0][tid] + ls[1][tid] + ls[2][tid] + ls[3][tid]);
  else if (tid < 32) {
    int o = tid - 16;
    atomicAdd(&sq2[o], lsq[0][o] + lsq[1][o] + lsq[2][o] + lsq[3][o]);
  }
}

// ---------------------------------------------------------------- BN2+relu: NHWC fp32 -> padded NHWC bf16 h2p
__global__ __launch_bounds__(256) void bnrelu2_k(const float* __restrict__ ws2,
                                                 const float* __restrict__ sum2, const float* __restrict__ sq2,
                                                 const float* __restrict__ g2, const float* __restrict__ b2,
                                                 u16* __restrict__ h2p) {
  __shared__ float s_scale[16], s_shift[16];
  int tid = threadIdx.x;
  if (tid < 16) {
    float m = sum2[tid] / BN_N;
    float var = sq2[tid] / BN_N - m * m;
    float sc = g2[tid] * rsqrtf(var + 1e-5f);
    s_scale[tid] = sc;
    s_shift[tid] = b2[tid] - m * sc;
  }
  __syncthreads();
  int p = blockIdx.x * 256 + tid;
  int b = p >> 12, r = p & 4095;
  int y = r >> 6, xx = r & 63;
  const float* src = ws2 + (size_t)p * 16;
  u16* dst = h2p + (size_t)(((b * 66) + y + 1) * 66 + xx + 1) * 16;
#pragma unroll
  for (int c4 = 0; c4 < 4; ++c4) {
    float4 v = *(const float4*)(src + c4 * 4);
    u16 o0 = f2bf(fmaxf(v.x * s_scale[c4*4]   + s_shift[c4*4],   0.f));
    u16 o1 = f2bf(fmaxf(v.y * s_scale[c4*4+1] + s_shift[c4*4+1], 0.f));
    u16 o2 = f2bf(fmaxf(v.z * s_scale[c4*4+2] + s_shift[c4*4+2], 0.f));
    u16 o3 = f2bf(fmaxf(v.w * s_scale[c4*4+3] + s_shift[c4*4+3], 0.f));
    *(ushort4*)(dst + c4 * 4) = make_ushort4(o0, o1, o2, o3);
  }
}

// ---------------------------------------------------------------- offconv: implicit GEMM bf16 MFMA, N=32(18), K=160, no LDS
__global__ __launch_bounds__(256) void offconv_mfma(const u16* __restrict__ h2p,
                                                    const u16* __restrict__ BswO,
                                                    const float* __restrict__ ob,
                                                    float* __restrict__ offs) {   // (64,18,64,64)
  const int tid = threadIdx.x;
  const int w = tid >> 6, l = tid & 63;
  const int b = blockIdx.y;
  const int y = (blockIdx.x << 1) + (w >> 1);
  const int x0w = (w & 1) << 5;
  const int lm = l & 15, lk = l >> 4;

  floatx4 acc[2][2];
#pragma unroll
  for (int mb = 0; mb < 2; ++mb)
#pragma unroll
    for (int nb = 0; nb < 2; ++nb)
      acc[mb][nb] = (floatx4){0.f, 0.f, 0.f, 0.f};

  const u16* hb = h2p + (size_t)b * 66 * 66 * 16;

#pragma unroll
  for (int kk = 0; kk < 5; ++kk) {
    int tap = kk * 2 + (lk >> 1);
    if (tap > 8) tap = 8;                     // pad lanes: B zero there
    const int dy = tap / 3, dx = tap - dy * 3;
    const int c0 = (lk & 1) << 3;
    const u16* rowp = hb + (size_t)(((y + dy) * 66) + x0w + lm + dx) * 16 + c0;
    short8 a0 = *(const short8*)(rowp);
    short8 a1 = *(const short8*)(rowp + 16 * 16);
    const u16* bp = BswO + (((kk * 4 + lk) * 32) + lm) * 8;
    short8 b0 = *(const short8*)(bp);
    short8 b1 = *(const short8*)(bp + 16 * 8);
    acc[0][0] = __builtin_amdgcn_mfma_f32_16x16x32_bf16(a0, b0, acc[0][0], 0, 0, 0);
    acc[0][1] = __builtin_amdgcn_mfma_f32_16x16x32_bf16(a0, b1, acc[0][1], 0, 0, 0);
    acc[1][0] = __builtin_amdgcn_mfma_f32_16x16x32_bf16(a1, b0, acc[1][0], 0, 0, 0);
    acc[1][1] = __builtin_amdgcn_mfma_f32_16x16x32_bf16(a1, b1, acc[1][1], 0, 0, 0);
  }

#pragma unroll
  for (int mb = 0; mb < 2; ++mb)
#pragma unroll
    for (int nb = 0; nb < 2; ++nb) {
      int oc = nb * 16 + lm;
      if (oc < 18) {
        float bias = ob[oc];
        floatx4 v = acc[mb][nb];
        v.x += bias; v.y += bias; v.z += bias; v.w += bias;
        float* dst = offs + (size_t)b * 73728 + (oc << 12) + (y << 6) + x0w + (mb << 4) + (lk << 2);
        *(floatx4*)dst = v;
      }
    }
}

// ---------------------------------------------------------------- deform: bilinear sample -> in-register A-frag -> MFMA (no LDS)
// K = 144 (tap*16+c) padded to 160, N = 16. Wave: 64 px (4 m-tiles).
__global__ __launch_bounds__(256) void deform_mfma(const u16* __restrict__ h2p,
                                                   const float* __restrict__ offs,
                                                   const u16* __restrict__ Bsw3,
                                                   float* __restrict__ out,      // NHWC (64,4096,16)
                                                   float* __restrict__ sum3, float* __restrict__ sq3) {
  const int tid = threadIdx.x;
  const int w = tid >> 6, l = tid & 63;
  const int lm = l & 15, lk = l >> 4;
  const int pbase = blockIdx.x * 256 + w * 64;   // wave's 64 pixels (same b)
  const int b = pbase >> 12;
  const u16* img = h2p + (size_t)b * 66 * 66 * 16;
  const float* offp = offs + (size_t)b * 73728;

  short8 bf[5];
#pragma unroll
  for (int kk = 0; kk < 5; ++kk)
    bf[kk] = *(const short8*)(Bsw3 + (((kk * 4 + lk) * 16) + lm) * 8);

  floatx4 acc[4];
#pragma unroll
  for (int mt = 0; mt < 4; ++mt) acc[mt] = (floatx4){0.f, 0.f, 0.f, 0.f};

#pragma unroll
  for (int mt = 0; mt < 4; ++mt) {
    const int p = pbase + mt * 16 + lm;     // this lane's A-row pixel
    const int r = p & 4095;
    const int y = r >> 6, x = r & 63;
#pragma unroll
    for (int kk = 0; kk < 5; ++kk) {
      const int k0 = kk * 32 + lk * 8;
      int tap = k0 >> 4;
      const int c0 = k0 & 15;               // 0 or 8
      if (tap > 8) tap = 8;                 // k-pad lanes: B zero kills the product
      const int dy = tap / 3, dx = tap - dy * 3;
      float offy = offp[(tap << 12) + r];
      float offx = offp[((tap + 9) << 12) + r];
      float py = (float)(y + dy) + offy;
      float px = (float)(x + dx) + offx;
      py = fminf(fmaxf(py, 0.f), 65.f);
      px = fminf(fmaxf(px, 0.f), 65.f);
      float y0f = floorf(py), x0f = floorf(px);
      int y0 = (int)y0f, x0 = (int)x0f;
      int y1 = min(y0 + 1, 65), x1 = min(x0 + 1, 65);
      float wy = py - y0f, wx = px - x0f;
      float w00 = (1.f - wy) * (1.f - wx), w01 = (1.f - wy) * wx;
      float w10 = wy * (1.f - wx),         w11 = wy * wx;
      short8 v00 = *(const short8*)(img + (y0 * 66 + x0) * 16 + c0);
      short8 v01 = *(const short8*)(img + (y0 * 66 + x1) * 16 + c0);
      short8 v10 = *(const short8*)(img + (y1 * 66 + x0) * 16 + c0);
      short8 v11 = *(const short8*)(img + (y1 * 66 + x1) * 16 + c0);
      short8 a;
#pragma unroll
      for (int j = 0; j < 8; ++j) {
        float s = bf2f((u16)v00[j]) * w00 + bf2f((u16)v01[j]) * w01
                + bf2f((u16)v10[j]) * w10 + bf2f((u16)v11[j]) * w11;
        a[j] = (short)f2bf(s);
      }
      acc[mt] = __builtin_amdgcn_mfma_f32_16x16x32_bf16(a, bf[kk], acc[mt], 0, 0, 0);
    }
  }

  // store NHWC: lane holds oc=lm for pixels (mt*16 + lk*4 + reg)
  float s = 0.f, s2 = 0.f;
#pragma unroll
  for (int mt = 0; mt < 4; ++mt) {
    floatx4 a = acc[mt];
    s += a.x + a.y + a.z + a.w;
    s2 += a.x * a.x + a.y * a.y + a.z * a.z + a.w * a.w;
#pragma unroll
    for (int reg = 0; reg < 4; ++reg) {
      int pp = pbase + mt * 16 + lk * 4 + reg;
      out[(size_t)pp * 16 + lm] = acc[mt][reg];
    }
  }
  // fused stats3
  __shared__ float ls[4][16], lsq[4][16];
  s += __shfl_xor(s, 16, 64);  s += __shfl_xor(s, 32, 64);
  s2 += __shfl_xor(s2, 16, 64); s2 += __shfl_xor(s2, 32, 64);
  if (lk == 0) { ls[w][lm] = s; lsq[w][lm] = s2; }
  __syncthreads();
  if (tid < 16) atomicAdd(&sum3[tid], ls[0][tid] + ls[1][tid] + ls[2][tid] + ls[3][tid]);
  else if (tid < 32) {
    int o = tid - 16;
    atomicAdd(&sq3[o], lsq[0][o] + lsq[1][o] + lsq[2][o] + lsq[3][o]);
  }
}

// ---------------------------------------------------------------- BN3+relu: NHWC fp32 -> padded NHWC bf16 h3p
__global__ __launch_bounds__(256) void bnrelu3_k(const float* __restrict__ wsd,
                                                 const float* __restrict__ sum3, const float* __restrict__ sq3,
                                                 const float* __restrict__ g3, const float* __restrict__ b3,
                                                 u16* __restrict__ h3p) {
  __shared__ float s_scale[16], s_shift[16];
  int tid = threadIdx.x;
  if (tid < 16) {
    float m = sum3[tid] / BN_N;
    float var = sq3[tid] / BN_N - m * m;
    float sc = g3[tid] * rsqrtf(var + 1e-5f);
    s_scale[tid] = sc;
    s_shift[tid] = b3[tid] - m * sc;
  }
  __syncthreads();
  int p = blockIdx.x * 256 + tid;
  int b = p >> 12, r = p & 4095;
  int y = r >> 6, xx = r & 63;
  const float* src = wsd + (size_t)p * 16;
  u16* dst = h3p + (size_t)(((b * 66) + y + 1) * 66 + xx + 1) * 16;
#pragma unroll
  for (int c4 = 0; c4 < 4; ++c4) {
    float4 v = *(const float4*)(src + c4 * 4);
    u16 o0 = f2bf(fmaxf(v.x * s_scale[c4*4]   + s_shift[c4*4],   0.f));
    u16 o1 = f2bf(fmaxf(v.y * s_scale[c4*4+1] + s_shift[c4*4+1], 0.f));
    u16 o2 = f2bf(fmaxf(v.z * s_scale[c4*4+2] + s_shift[c4*4+2], 0.f));
    u16 o3 = f2bf(fmaxf(v.w * s_scale[c4*4+3] + s_shift[c4*4+3], 0.f));
    *(ushort4*)(dst + c4 * 4) = make_ushort4(o0, o1, o2, o3);
  }
}

// ---------------------------------------------------------------- conv4 implicit GEMM bf16 MFMA + fused stats4
__global__ __launch_bounds__(256) void conv4_mfma(const u16* __restrict__ h3p,
                                                  const u16* __restrict__ Bsw4,
                                                  u16* __restrict__ h4,
                                                  float* __restrict__ sum4, float* __restrict__ sq4) {
  const int tid = threadIdx.x;
  const int w = tid >> 6, l = tid & 63;
  const int b = blockIdx.y;
  const int y = (blockIdx.x << 1) + (w >> 1);
  const int x0w = (w & 1) << 5;
  const int lm = l & 15, lk = l >> 4;

  floatx4 acc[2][4];
#pragma unroll
  for (int mb = 0; mb < 2; ++mb)
#pragma unroll
    for (int nb = 0; nb < 4; ++nb)
      acc[mb][nb] = (floatx4){0.f, 0.f, 0.f, 0.f};

  const u16* hb = h3p + (size_t)b * 66 * 66 * 16;

#pragma unroll
  for (int kk = 0; kk < 5; ++kk) {
    int tap = kk * 2 + (lk >> 1);
    if (tap > 8) tap = 8;
    const int dy = tap / 3, dx = tap - dy * 3;
    const int c0 = (lk & 1) << 3;
    const u16* rowp = hb + (size_t)(((y + dy) * 66) + x0w + lm + dx) * 16 + c0;
    short8 a0 = *(const short8*)(rowp);
    short8 a1 = *(const short8*)(rowp + 16 * 16);
    const u16* bp = Bsw4 + (((kk * 4 + lk) * 64) + lm) * 8;
    short8 b0 = *(const short8*)(bp);
    short8 b1 = *(const short8*)(bp + 16 * 8);
    short8 b2 = *(const short8*)(bp + 32 * 8);
    short8 b3 = *(const short8*)(bp + 48 * 8);
    acc[0][0] = __builtin_amdgcn_mfma_f32_16x16x32_bf16(a0, b0, acc[0][0], 0, 0, 0);
    acc[0][1] = __builtin_amdgcn_mfma_f32_16x16x32_bf16(a0, b1, acc[0][1], 0, 0, 0);
    acc[0][2] = __builtin_amdgcn_mfma_f32_16x16x32_bf16(a0, b2, acc[0][2], 0, 0, 0);
    acc[0][3] = __builtin_amdgcn_mfma_f32_16x16x32_bf16(a0, b3, acc[0][3], 0, 0, 0);
    acc[1][0] = __builtin_amdgcn_mfma_f32_16x16x32_bf16(a1, b0, acc[1][0], 0, 0, 0);
    acc[1][1] = __builtin_amdgcn_mfma_f32_16x16x32_bf16(a1, b1, acc[1][1], 0, 0, 0);
    acc[1][2] = __builtin_amdgcn_mfma_f32_16x16x32_bf16(a1, b2, acc[1][2], 0, 0, 0);
    acc[1][3] = __builtin_amdgcn_mfma_f32_16x16x32_bf16(a1, b3, acc[1][3], 0, 0, 0);
  }

#pragma unroll
  for (int mb = 0; mb < 2; ++mb)
#pragma unroll
    for (int nb = 0; nb < 4; ++nb) {
      u16* dst = h4 + ((size_t)(b * 64 + nb * 16 + lm) << 12) + (y << 6) + x0w + (mb << 4) + (lk << 2);
      floatx4 v = acc[mb][nb];
      *(ushort4*)dst = make_ushort4(f2bf(v.x), f2bf(v.y), f2bf(v.z), f2bf(v.w));
    }

  // fused stats4 (from fp32 acc)
  __shared__ float lsum[4][64], lsq[4][64];
  float s[4], s2[4];
#pragma unroll
  for (int nb = 0; nb < 4; ++nb) {
    s[nb] = 0.f; s2[nb] = 0.f;
#pragma unroll
    for (int mb = 0; mb < 2; ++mb) {
      floatx4 a = acc[mb][nb];
      s[nb] += a.x + a.y + a.z + a.w;
      s2[nb] += a.x * a.x + a.y * a.y + a.z * a.z + a.w * a.w;
    }
    s[nb] += __shfl_xor(s[nb], 16, 64);  s[nb] += __shfl_xor(s[nb], 32, 64);
    s2[nb] += __shfl_xor(s2[nb], 16, 64); s2[nb] += __shfl_xor(s2[nb], 32, 64);
  }
  if (lk == 0) {
#pragma unroll
    for (int nb = 0; nb < 4; ++nb) { lsum[w][nb * 16 + lm] = s[nb]; lsq[w][nb * 16 + lm] = s2[nb]; }
  }
  __syncthreads();
  if (tid < 64) atomicAdd(&sum4[tid], lsum[0][tid] + lsum[1][tid] + lsum[2][tid] + lsum[3][tid]);
  else if (tid < 128) { int o = tid - 64; atomicAdd(&sq4[o], lsq[0][o] + lsq[1][o] + lsq[2][o] + lsq[3][o]); }
}

// ---------------------------------------------------------------- final: BN4 + residual + relu (h4 bf16 -> out fp32)
__global__ __launch_bounds__(256) void final_k(const u16* __restrict__ h4,
                                               float* __restrict__ out,
                                               const float* __restrict__ x,
                                               const float* __restrict__ sum4, const float* __restrict__ sq4,
                                               const float* __restrict__ g4, const float* __restrict__ b4) {
  __shared__ float s_scale[64], s_shift[64];
  int tid = threadIdx.x;
  if (tid < 64) {
    float m = sum4[tid] / BN_N;
    float var = sq4[tid] / BN_N - m * m;
    float sc = g4[tid] * rsqrtf(var + 1e-5f);
    s_scale[tid] = sc;
    s_shift[tid] = b4[tid] - m * sc;
  }
  __syncthreads();
  int i = (blockIdx.x * 256 + tid) * 4;
  int c = (i >> 12) & 63;
  ushort4 q = *(const ushort4*)(h4 + i);
  float4 xv = *(const float4*)(x + i);
  float sc = s_scale[c], sh = s_shift[c];
  float4 v;
  v.x = fmaxf(bf2f(q.x) * sc + sh + xv.x, 0.f);
  v.y = fmaxf(bf2f(q.y) * sc + sh + xv.y, 0.f);
  v.z = fmaxf(bf2f(q.z) * sc + sh + xv.z, 0.f);
  v.w = fmaxf(bf2f(q.w) * sc + sh + xv.w, 0.f);
  *(float4*)(out + i) = v;
}

extern "C" void kernel_launch(void* const* d_in, const int* in_sizes, int n_in,
                              void* d_out, int out_size, void* d_ws, size_t ws_size,
                              hipStream_t stream) {
  const float* x  = (const float*)d_in[0];
  const float* w1 = (const float*)d_in[1];
  const float* g1 = (const float*)d_in[2];
  const float* b1 = (const float*)d_in[3];
  const float* w2 = (const float*)d_in[4];
  const float* g2 = (const float*)d_in[5];
  const float* b2 = (const float*)d_in[6];
  const float* ow = (const float*)d_in[7];
  const float* ob = (const float*)d_in[8];
  const float* w3 = (const float*)d_in[9];
  const float* g3 = (const float*)d_in[10];
  const float* b3 = (const float*)d_in[11];
  const float* w4 = (const float*)d_in[12];
  const float* g4 = (const float*)d_in[13];
  const float* b4 = (const float*)d_in[14];
  float* out = (float*)d_out;
  float* ws = (float*)d_ws;

  // workspace layout (float offsets):
  //   offs  (64,18,4096) fp32          4,718,592   dead after deform -> h4 (bf16) overlays
  //   wsd   NHWC fp32 (64,4096,16)     4,194,304
  //   ws2   NHWC fp32 (64,4096,16)     4,194,304
  //   h2p   padded NHWC bf16 (66^2,16) region reserved 4,460,544 floats (uses half)
  //         h3p SHARES this buffer: borders stay zero from one memset; interior
  //         overwritten by bnrelu3 after deform's last read (stream-ordered).
  //   stats 320
  //   Bsw(36864) Bsw4(10240) Bsw3(2560) BswO(5120)  u16
  // xp (bf16 input, = float[0..8,921,088)) overlays offs+wsd+ws2-head; dead after conv1.
  float* offs = ws;
  float* wsd  = offs + 4718592;
  float* ws2  = wsd + 4194304;
  float* h2pf = ws2 + 4194304;
  float* stats = h2pf + 4460544;
  float* sum1 = stats, *sq1 = stats + 64;
  float* sum2 = stats + 128, *sq2 = stats + 144;
  float* sum3 = stats + 160, *sq3 = stats + 176;
  float* sum4 = stats + 192, *sq4 = stats + 256;
  u16* xp   = (u16*)ws;
  u16* Bsw  = (u16*)(stats + 320);
  u16* Bsw4 = Bsw + 36864;
  u16* Bsw3 = Bsw4 + 10240;
  u16* BswO = Bsw3 + 2560;
  u16* h2p  = (u16*)h2pf;    // bf16 padded NHWC (64,66,66,16); doubles as h3p
  u16* h4   = (u16*)offs;    // bf16 NCHW conv4 raw, overlays dead offs

  hipMemsetAsync(stats, 0, 320 * sizeof(float), stream);
  hipMemsetAsync(h2p, 0, 4460544 * sizeof(u16), stream);

  prep_w_k<<<144, 256, 0, stream>>>(w1, Bsw);
  prep_w4_k<<<40, 256, 0, stream>>>(w4, Bsw4);
  prep_w3_k<<<10, 256, 0, stream>>>(w3, Bsw3);
  prep_wo_k<<<20, 256, 0, stream>>>(ow, BswO);
  prep_x_k<<<dim3(66, 64), 256, 0, stream>>>(x, xp);
  conv1_mfma<<<dim3(32, 64), 256, 0, stream>>>(xp, Bsw, out, sum1, sq1);
  conv2_k<<<1024, 256, 0, stream>>>(out, w2, sum1, sq1, g1, b1, ws2, sum2, sq2);
  bnrelu2_k<<<1024, 256, 0, stream>>>(ws2, sum2, sq2, g2, b2, h2p);
  offconv_mfma<<<dim3(32, 64), 256, 0, stream>>>(h2p, BswO, ob, offs);
  deform_mfma<<<1024, 256, 0, stream>>>(h2p, offs, Bsw3, wsd, sum3, sq3);
  bnrelu3_k<<<1024, 256, 0, stream>>>(wsd, sum3, sq3, g3, b3, h2p /* = h3p */);
  conv4_mfma<<<dim3(32, 64), 256, 0, stream>>>(h2p, Bsw4, h4, sum4, sq4);
  final_k<<<16384, 256, 0, stream>>>(h4, out, x, sum4, sq4, g4, b4);
}

// Round 5
// 361.512 us; speedup vs baseline: 6.1991x; 1.0994x over previous
//
#include <hip/hip_runtime.h>

// B=64, Cin=P=64, H=W=64, mid C=16, offsets C=18, K=3x3.  BN n = 262144
#define BN_N 262144.0f

typedef unsigned short u16;
typedef __attribute__((ext_vector_type(8))) short short8;   // 8 x bf16
typedef __attribute__((ext_vector_type(4))) float floatx4;

static __device__ __forceinline__ u16 f2bf(float f) {
  union { float f; unsigned u; } v; v.f = f;
  unsigned u = v.u;
  return (u16)((u + 0x7FFFu + ((u >> 16) & 1u)) >> 16);
}
static __device__ __forceinline__ float bf2f(u16 h) {
  union { unsigned u; float f; } v; v.u = ((unsigned)h) << 16;
  return v.f;
}

// ---------------------------------------------------------------- prep: w1 -> swizzled bf16 B (conv1, K=576)
__global__ __launch_bounds__(256) void prep_w_k(const float* __restrict__ w1,
                                                u16* __restrict__ Bsw) {
  int d = blockIdx.x * 256 + threadIdx.x;   // 0..36863
  int kin = d & 7, n = (d >> 3) & 63, kgrp = (d >> 9) & 3, kc = d >> 11;
  int k = kc * 32 + kgrp * 8 + kin;
  int tap = k >> 6, c = k & 63;
  Bsw[d] = f2bf(w1[n * 576 + c * 9 + tap]);
}

// ---------------------------------------------------------------- prep: w4 -> swizzled bf16 B (conv4, K=144->160)
__global__ __launch_bounds__(256) void prep_w4_k(const float* __restrict__ w4,
                                                 u16* __restrict__ Bsw4) {
  int d = blockIdx.x * 256 + threadIdx.x;   // 0..10239
  if (d >= 10240) return;
  int kin = d & 7, n = (d >> 3) & 63, lk = (d >> 9) & 3, kk = d >> 11;
  int tap = kk * 2 + (lk >> 1);
  int c = ((lk & 1) << 3) + kin;
  float v = (tap < 9) ? w4[n * 144 + c * 9 + tap] : 0.f;
  Bsw4[d] = f2bf(v);
}

// ---------------------------------------------------------------- prep: w3 -> swizzled bf16 B (deform, K=144->160, N=16)
__global__ __launch_bounds__(256) void prep_w3_k(const float* __restrict__ w3,
                                                 u16* __restrict__ Bsw3) {
  int d = blockIdx.x * 256 + threadIdx.x;   // 0..2559
  if (d >= 2560) return;
  int kin = d & 7, n = (d >> 3) & 15, lk = (d >> 7) & 3, kk = d >> 9;
  int k = kk * 32 + lk * 8 + kin;
  int tap = k >> 4, c = k & 15;
  float v = (tap < 9) ? w3[n * 144 + c * 9 + tap] : 0.f;
  Bsw3[d] = f2bf(v);
}

// ---------------------------------------------------------------- prep: ow -> swizzled bf16 B (offconv, K=144->160, N=18->32)
__global__ __launch_bounds__(256) void prep_wo_k(const float* __restrict__ ow,
                                                 u16* __restrict__ BswO) {
  int d = blockIdx.x * 256 + threadIdx.x;   // 0..5119
  if (d >= 5120) return;
  int kin = d & 7, n = (d >> 3) & 31, lk = (d >> 8) & 3, kk = d >> 10;
  int tap = kk * 2 + (lk >> 1);
  int c = ((lk & 1) << 3) + kin;
  float v = (tap < 9 && n < 18) ? ow[n * 144 + c * 9 + tap] : 0.f;
  BswO[d] = f2bf(v);
}

// ---------------------------------------------------------------- prep: x -> padded NHWC bf16 (64,66,66,64)
__global__ __launch_bounds__(256) void prep_x_k(const float* __restrict__ x,
                                                u16* __restrict__ xp) {
  int yp = blockIdx.x;   // 0..65
  int b = blockIdx.y;
  int tid = threadIdx.x;
  u16* rowbase = xp + ((size_t)(b * 66 + yp)) * 66 * 64;
  if (yp == 0 || yp == 65) {
    for (int i = tid; i < 1056; i += 256)
      ((ushort4*)rowbase)[i] = make_ushort4(0, 0, 0, 0);
    return;
  }
  int y = yp - 1;
  __shared__ u16 s[64][68];
  for (int i = tid; i < 4096; i += 256) {
    int c = i >> 6, xx = i & 63;
    s[xx][c] = f2bf(x[((b * 64 + c) << 12) + (y << 6) + xx]);
  }
  if (tid < 128) {
    int c = tid & 63;
    int xpad = (tid >> 6) ? 65 : 0;
    rowbase[xpad * 64 + c] = 0;
  }
  __syncthreads();
  for (int j = tid; j < 1024; j += 256) {
    int xx = j >> 4, c4 = (j & 15) << 2;
    *(ushort4*)(rowbase + (xx + 1) * 64 + c4) =
        make_ushort4(s[xx][c4], s[xx][c4 + 1], s[xx][c4 + 2], s[xx][c4 + 3]);
  }
}

// ---------------------------------------------------------------- conv1 implicit GEMM bf16 MFMA, prefetch-pipelined
// Wave = one 64-px row x 64 oc. K = 576, 18 iters. Register double-buffer:
// kk+1's 8 fragment loads issue BEFORE kk's 16 MFMAs (forces ~140 VGPR, MLP).
__global__ __launch_bounds__(256) void conv1_mfma(const u16* __restrict__ xp,
                                                  const u16* __restrict__ Bsw,
                                                  u16* __restrict__ h1,        // bf16 NCHW raw
                                                  float* __restrict__ sum1, float* __restrict__ sq1) {
  const int tid = threadIdx.x;
  const int w = tid >> 6, l = tid & 63;
  const int lm = l & 15, lk = l >> 4;
  const int b = blockIdx.x >> 4;
  const int y = ((blockIdx.x & 15) << 2) + w;
  const u16* xpb = xp + (size_t)b * 66 * 66 * 64;

  floatx4 acc[4][4];
#pragma unroll
  for (int mt = 0; mt < 4; ++mt)
#pragma unroll
    for (int nb = 0; nb < 4; ++nb)
      acc[mt][nb] = (floatx4){0.f, 0.f, 0.f, 0.f};

  short8 aC[4], bC[4], aN[4], bN[4];

#define C1_LOAD(KK, A, BV)                                              \
  {                                                                     \
    const int tap_ = (KK) >> 1;                                         \
    const int dy_ = tap_ / 3, dx_ = tap_ - dy_ * 3;                     \
    const int c0_ = (((KK) & 1) << 5) + (lk << 3);                      \
    const u16* rowp_ = xpb + (((y + dy_) * 66) + lm + dx_) * 64 + c0_;  \
    A[0] = *(const short8*)(rowp_);                                     \
    A[1] = *(const short8*)(rowp_ + 16 * 64);                           \
    A[2] = *(const short8*)(rowp_ + 32 * 64);                           \
    A[3] = *(const short8*)(rowp_ + 48 * 64);                           \
    const u16* bp_ = Bsw + ((((KK) * 4 + lk) * 64) + lm) * 8;           \
    BV[0] = *(const short8*)(bp_);                                      \
    BV[1] = *(const short8*)(bp_ + 128);                                \
    BV[2] = *(const short8*)(bp_ + 256);                                \
    BV[3] = *(const short8*)(bp_ + 384);                                \
  }

  C1_LOAD(0, aC, bC)
#pragma unroll
  for (int kk = 0; kk < 18; ++kk) {
    if (kk < 17) C1_LOAD(kk + 1, aN, bN)
#pragma unroll
    for (int mt = 0; mt < 4; ++mt)
#pragma unroll
      for (int nb = 0; nb < 4; ++nb)
        acc[mt][nb] = __builtin_amdgcn_mfma_f32_16x16x32_bf16(aC[mt], bC[nb], acc[mt][nb], 0, 0, 0);
#pragma unroll
    for (int i = 0; i < 4; ++i) { aC[i] = aN[i]; bC[i] = bN[i]; }
  }
#undef C1_LOAD

  // store bf16 NCHW: lane oc = nb*16+lm, pixel x = mt*16 + lk*4 + reg
#pragma unroll
  for (int mt = 0; mt < 4; ++mt)
#pragma unroll
    for (int nb = 0; nb < 4; ++nb) {
      u16* dst = h1 + ((size_t)(b * 64 + nb * 16 + lm) << 12) + (y << 6) + mt * 16 + (lk << 2);
      floatx4 v = acc[mt][nb];
      *(ushort4*)dst = make_ushort4(f2bf(v.x), f2bf(v.y), f2bf(v.z), f2bf(v.w));
    }

  // fused stats1 (fp32 acc)
  __shared__ float lsum[4][64], lsq[4][64];
  float s[4], s2[4];
#pragma unroll
  for (int nb = 0; nb < 4; ++nb) {
    s[nb] = 0.f; s2[nb] = 0.f;
#pragma unroll
    for (int mt = 0; mt < 4; ++mt) {
      floatx4 a = acc[mt][nb];
      s[nb] += a.x + a.y + a.z + a.w;
      s2[nb] += a.x * a.x + a.y * a.y + a.z * a.z + a.w * a.w;
    }
    s[nb] += __shfl_xor(s[nb], 16, 64);  s[nb] += __shfl_xor(s[nb], 32, 64);
    s2[nb] += __shfl_xor(s2[nb], 16, 64); s2[nb] += __shfl_xor(s2[nb], 32, 64);
  }
  if (lk == 0) {
#pragma unroll
    for (int nb = 0; nb < 4; ++nb) { lsum[w][nb * 16 + lm] = s[nb]; lsq[w][nb * 16 + lm] = s2[nb]; }
  }
  __syncthreads();
  if (tid < 64) atomicAdd(&sum1[tid], lsum[0][tid] + lsum[1][tid] + lsum[2][tid] + lsum[3][tid]);
  else if (tid < 128) { int o = tid - 64; atomicAdd(&sq1[o], lsq[0][o] + lsq[1][o] + lsq[2][o] + lsq[3][o]); }
}

// ---------------------------------------------------------------- conv2: 1x1 64->16 (bf16 h1 in), BN1+relu, NHWC out + stats2
__global__ __launch_bounds__(256) void conv2_k(const u16* __restrict__ h1,
                                               const float* __restrict__ w2,
                                               const float* __restrict__ sum1, const float* __restrict__ sq1,
                                               const float* __restrict__ g1, const float* __restrict__ b1,
                                               float* __restrict__ out,        // NHWC (64,4096,16)
                                               float* __restrict__ sum2, float* __restrict__ sq2) {
  __shared__ float s_wt[64 * 16];
  __shared__ float s_scale[64], s_shift[64];
  __shared__ float ls[4][16], lsq[4][16];
  int tid = threadIdx.x;
  for (int i = tid; i < 1024; i += 256) {
    int o = i >> 6, c = i & 63;
    s_wt[c * 16 + o] = w2[i];
  }
  if (tid < 64) {
    float m = sum1[tid] / BN_N;
    float var = sq1[tid] / BN_N - m * m;
    float sc = g1[tid] * rsqrtf(var + 1e-5f);
    s_scale[tid] = sc;
    s_shift[tid] = b1[tid] - m * sc;
  }
  __syncthreads();
  int p = blockIdx.x * 256 + tid;
  int b = p >> 12, r = p & 4095;
  const u16* src = h1 + ((size_t)b << 18) + r;
  float acc[16];
#pragma unroll
  for (int o = 0; o < 16; ++o) acc[o] = 0.f;
  for (int c = 0; c < 64; ++c) {
    float v = bf2f(src[c << 12]);
    v = fmaxf(v * s_scale[c] + s_shift[c], 0.f);
    const float* wp = &s_wt[c * 16];
    float4 w0 = *(const float4*)wp;
    float4 w1 = *(const float4*)(wp + 4);
    float4 w2v = *(const float4*)(wp + 8);
    float4 w3v = *(const float4*)(wp + 12);
    acc[0] += w0.x * v;  acc[1] += w0.y * v;  acc[2] += w0.z * v;  acc[3] += w0.w * v;
    acc[4] += w1.x * v;  acc[5] += w1.y * v;  acc[6] += w1.z * v;  acc[7] += w1.w * v;
    acc[8] += w2v.x * v; acc[9] += w2v.y * v; acc[10] += w2v.z * v; acc[11] += w2v.w * v;
    acc[12] += w3v.x * v; acc[13] += w3v.y * v; acc[14] += w3v.z * v; acc[15] += w3v.w * v;
  }
  float* dst = out + (size_t)p * 16;
#pragma unroll
  for (int c4 = 0; c4 < 4; ++c4)
    *(float4*)(dst + c4 * 4) = make_float4(acc[c4*4], acc[c4*4+1], acc[c4*4+2], acc[c4*4+3]);
  int lane = tid & 63, wv = tid >> 6;
#pragma unroll
  for (int o = 0; o < 16; ++o) {
    float s = acc[o], s2 = acc[o] * acc[o];
#pragma unroll
    for (int off = 32; off > 0; off >>= 1) {
      s += __shfl_down(s, off, 64);
      s2 += __shfl_down(s2, off, 64);
    }
    if (lane == 0) { ls[wv][o] = s; lsq[wv][o] = s2; }
  }
  __syncthreads();
  if (tid < 16) atomicAdd(&sum2[tid], ls[0][tid] + ls[1][tid] + ls[2][tid] + ls[3][tid]);
  else if (tid < 32) {
    int o = tid - 16;
    atomicAdd(&sq2[o], lsq[0][o] + lsq[1][o] + lsq[2][o] + lsq[3][o]);
  }
}

// ---------------------------------------------------------------- BN2+relu: NHWC fp32 -> padded NHWC bf16 h2p
__global__ __launch_bounds__(256) void bnrelu2_k(const float* __restrict__ ws2,
                                                 const float* __restrict__ sum2, const float* __restrict__ sq2,
                                                 const float* __restrict__ g2, const float* __restrict__ b2,
                                                 u16* __restrict__ h2p) {
  __shared__ float s_scale[16], s_shift[16];
  int tid = threadIdx.x;
  if (tid < 16) {
    float m = sum2[tid] / BN_N;
    float var = sq2[tid] / BN_N - m * m;
    float sc = g2[tid] * rsqrtf(var + 1e-5f);
    s_scale[tid] = sc;
    s_shift[tid] = b2[tid] - m * sc;
  }
  __syncthreads();
  int p = blockIdx.x * 256 + tid;
  int b = p >> 12, r = p & 4095;
  int y = r >> 6, xx = r & 63;
  const float* src = ws2 + (size_t)p * 16;
  u16* dst = h2p + (size_t)(((b * 66) + y + 1) * 66 + xx + 1) * 16;
#pragma unroll
  for (int c4 = 0; c4 < 4; ++c4) {
    float4 v = *(const float4*)(src + c4 * 4);
    u16 o0 = f2bf(fmaxf(v.x * s_scale[c4*4]   + s_shift[c4*4],   0.f));
    u16 o1 = f2bf(fmaxf(v.y * s_scale[c4*4+1] + s_shift[c4*4+1], 0.f));
    u16 o2 = f2bf(fmaxf(v.z * s_scale[c4*4+2] + s_shift[c4*4+2], 0.f));
    u16 o3 = f2bf(fmaxf(v.w * s_scale[c4*4+3] + s_shift[c4*4+3], 0.f));
    *(ushort4*)(dst + c4 * 4) = make_ushort4(o0, o1, o2, o3);
  }
}

// ---------------------------------------------------------------- offconv: implicit GEMM, N=32(18), K=160, prefetch-pipelined
__global__ __launch_bounds__(256) void offconv_mfma(const u16* __restrict__ h2p,
                                                    const u16* __restrict__ BswO,
                                                    const float* __restrict__ ob,
                                                    float* __restrict__ offs) {   // (64,18,64,64)
  const int tid = threadIdx.x;
  const int w = tid >> 6, l = tid & 63;
  const int lm = l & 15, lk = l >> 4;
  const int b = blockIdx.x >> 4;
  const int y = ((blockIdx.x & 15) << 2) + w;
  const u16* hb = h2p + (size_t)b * 66 * 66 * 16;

  floatx4 acc[4][2];
#pragma unroll
  for (int mt = 0; mt < 4; ++mt)
#pragma unroll
    for (int nb = 0; nb < 2; ++nb)
      acc[mt][nb] = (floatx4){0.f, 0.f, 0.f, 0.f};

  short8 aC[4], bC[2], aN[4], bN[2];

#define OC_LOAD(KK, A, BV)                                                    \
  {                                                                           \
    int tap_ = (KK) * 2 + (lk >> 1);                                          \
    if (tap_ > 8) tap_ = 8;                                                   \
    const int dy_ = tap_ / 3, dx_ = tap_ - dy_ * 3;                           \
    const int c0_ = (lk & 1) << 3;                                            \
    const u16* rowp_ = hb + (size_t)(((y + dy_) * 66) + lm + dx_) * 16 + c0_; \
    A[0] = *(const short8*)(rowp_);                                           \
    A[1] = *(const short8*)(rowp_ + 16 * 16);                                 \
    A[2] = *(const short8*)(rowp_ + 32 * 16);                                 \
    A[3] = *(const short8*)(rowp_ + 48 * 16);                                 \
    const u16* bp_ = BswO + ((((KK) * 4 + lk) * 32) + lm) * 8;                \
    BV[0] = *(const short8*)(bp_);                                            \
    BV[1] = *(const short8*)(bp_ + 128);                                      \
  }

  OC_LOAD(0, aC, bC)
#pragma unroll
  for (int kk = 0; kk < 5; ++kk) {
    if (kk < 4) OC_LOAD(kk + 1, aN, bN)
#pragma unroll
    for (int mt = 0; mt < 4; ++mt)
#pragma unroll
      for (int nb = 0; nb < 2; ++nb)
        acc[mt][nb] = __builtin_amdgcn_mfma_f32_16x16x32_bf16(aC[mt], bC[nb], acc[mt][nb], 0, 0, 0);
#pragma unroll
    for (int i = 0; i < 4; ++i) aC[i] = aN[i];
    bC[0] = bN[0]; bC[1] = bN[1];
  }
#undef OC_LOAD

#pragma unroll
  for (int mt = 0; mt < 4; ++mt)
#pragma unroll
    for (int nb = 0; nb < 2; ++nb) {
      int oc = nb * 16 + lm;
      if (oc < 18) {
        float bias = ob[oc];
        floatx4 v = acc[mt][nb];
        v.x += bias; v.y += bias; v.z += bias; v.w += bias;
        float* dst = offs + (size_t)b * 73728 + (oc << 12) + (y << 6) + mt * 16 + (lk << 2);
        *(floatx4*)dst = v;
      }
    }
}

// ---------------------------------------------------------------- deform: bilinear sample -> in-register A-frag -> MFMA
__global__ __launch_bounds__(256) void deform_mfma(const u16* __restrict__ h2p,
                                                   const float* __restrict__ offs,
                                                   const u16* __restrict__ Bsw3,
                                                   float* __restrict__ out,      // NHWC (64,4096,16)
                                                   float* __restrict__ sum3, float* __restrict__ sq3) {
  const int tid = threadIdx.x;
  const int w = tid >> 6, l = tid & 63;
  const int lm = l & 15, lk = l >> 4;
  const int pbase = blockIdx.x * 256 + w * 64;
  const int b = pbase >> 12;
  const u16* img = h2p + (size_t)b * 66 * 66 * 16;
  const float* offp = offs + (size_t)b * 73728;

  short8 bf[5];
#pragma unroll
  for (int kk = 0; kk < 5; ++kk)
    bf[kk] = *(const short8*)(Bsw3 + (((kk * 4 + lk) * 16) + lm) * 8);

  floatx4 acc[4];
#pragma unroll
  for (int mt = 0; mt < 4; ++mt) acc[mt] = (floatx4){0.f, 0.f, 0.f, 0.f};

#pragma unroll
  for (int mt = 0; mt < 4; ++mt) {
    const int p = pbase + mt * 16 + lm;
    const int r = p & 4095;
    const int y = r >> 6, x = r & 63;
#pragma unroll
    for (int kk = 0; kk < 5; ++kk) {
      const int k0 = kk * 32 + lk * 8;
      int tap = k0 >> 4;
      const int c0 = k0 & 15;
      if (tap > 8) tap = 8;
      const int dy = tap / 3, dx = tap - dy * 3;
      float offy = offp[(tap << 12) + r];
      float offx = offp[((tap + 9) << 12) + r];
      float py = (float)(y + dy) + offy;
      float px = (float)(x + dx) + offx;
      py = fminf(fmaxf(py, 0.f), 65.f);
      px = fminf(fmaxf(px, 0.f), 65.f);
      float y0f = floorf(py), x0f = floorf(px);
      int y0 = (int)y0f, x0 = (int)x0f;
      int y1 = min(y0 + 1, 65), x1 = min(x0 + 1, 65);
      float wy = py - y0f, wx = px - x0f;
      float w00 = (1.f - wy) * (1.f - wx), w01 = (1.f - wy) * wx;
      float w10 = wy * (1.f - wx),         w11 = wy * wx;
      short8 v00 = *(const short8*)(img + (y0 * 66 + x0) * 16 + c0);
      short8 v01 = *(const short8*)(img + (y0 * 66 + x1) * 16 + c0);
      short8 v10 = *(const short8*)(img + (y1 * 66 + x0) * 16 + c0);
      short8 v11 = *(const short8*)(img + (y1 * 66 + x1) * 16 + c0);
      short8 a;
#pragma unroll
      for (int j = 0; j < 8; ++j) {
        float s = bf2f((u16)v00[j]) * w00 + bf2f((u16)v01[j]) * w01
                + bf2f((u16)v10[j]) * w10 + bf2f((u16)v11[j]) * w11;
        a[j] = (short)f2bf(s);
      }
      acc[mt] = __builtin_amdgcn_mfma_f32_16x16x32_bf16(a, bf[kk], acc[mt], 0, 0, 0);
    }
  }

  float s = 0.f, s2 = 0.f;
#pragma unroll
  for (int mt = 0; mt < 4; ++mt) {
    floatx4 a = acc[mt];
    s += a.x + a.y + a.z + a.w;
    s2 += a.x * a.x + a.y * a.y + a.z * a.z + a.w * a.w;
#pragma unroll
    for (int reg = 0; reg < 4; ++reg) {
      int pp = pbase + mt * 16 + lk * 4 + reg;
      out[(size_t)pp * 16 + lm] = acc[mt][reg];
    }
  }
  __shared__ float ls[4][16], lsq[4][16];
  s += __shfl_xor(s, 16, 64);  s += __shfl_xor(s, 32, 64);
  s2 += __shfl_xor(s2, 16, 64); s2 += __shfl_xor(s2, 32, 64);
  if (lk == 0) { ls[w][lm] = s; lsq[w][lm] = s2; }
  __syncthreads();
  if (tid < 16) atomicAdd(&sum3[tid], ls[0][tid] + ls[1][tid] + ls[2][tid] + ls[3][tid]);
  else if (tid < 32) {
    int o = tid - 16;
    atomicAdd(&sq3[o], lsq[0][o] + lsq[1][o] + lsq[2][o] + lsq[3][o]);
  }
}

// ---------------------------------------------------------------- BN3+relu: NHWC fp32 -> padded NHWC bf16 h3p
__global__ __launch_bounds__(256) void bnrelu3_k(const float* __restrict__ wsd,
                                                 const float* __restrict__ sum3, const float* __restrict__ sq3,
                                                 const float* __restrict__ g3, const float* __restrict__ b3,
                                                 u16* __restrict__ h3p) {
  __shared__ float s_scale[16], s_shift[16];
  int tid = threadIdx.x;
  if (tid < 16) {
    float m = sum3[tid] / BN_N;
    float var = sq3[tid] / BN_N - m * m;
    float sc = g3[tid] * rsqrtf(var + 1e-5f);
    s_scale[tid] = sc;
    s_shift[tid] = b3[tid] - m * sc;
  }
  __syncthreads();
  int p = blockIdx.x * 256 + tid;
  int b = p >> 12, r = p & 4095;
  int y = r >> 6, xx = r & 63;
  const float* src = wsd + (size_t)p * 16;
  u16* dst = h3p + (size_t)(((b * 66) + y + 1) * 66 + xx + 1) * 16;
#pragma unroll
  for (int c4 = 0; c4 < 4; ++c4) {
    float4 v = *(const float4*)(src + c4 * 4);
    u16 o0 = f2bf(fmaxf(v.x * s_scale[c4*4]   + s_shift[c4*4],   0.f));
    u16 o1 = f2bf(fmaxf(v.y * s_scale[c4*4+1] + s_shift[c4*4+1], 0.f));
    u16 o2 = f2bf(fmaxf(v.z * s_scale[c4*4+2] + s_shift[c4*4+2], 0.f));
    u16 o3 = f2bf(fmaxf(v.w * s_scale[c4*4+3] + s_shift[c4*4+3], 0.f));
    *(ushort4*)(dst + c4 * 4) = make_ushort4(o0, o1, o2, o3);
  }
}

// ---------------------------------------------------------------- conv4 implicit GEMM, K=160, prefetch-pipelined + stats4
__global__ __launch_bounds__(256) void conv4_mfma(const u16* __restrict__ h3p,
                                                  const u16* __restrict__ Bsw4,
                                                  u16* __restrict__ h4,
                                                  float* __restrict__ sum4, float* __restrict__ sq4) {
  const int tid = threadIdx.x;
  const int w = tid >> 6, l = tid & 63;
  const int lm = l & 15, lk = l >> 4;
  const int b = blockIdx.x >> 4;
  const int y = ((blockIdx.x & 15) << 2) + w;
  const u16* hb = h3p + (size_t)b * 66 * 66 * 16;

  floatx4 acc[4][4];
#pragma unroll
  for (int mt = 0; mt < 4; ++mt)
#pragma unroll
    for (int nb = 0; nb < 4; ++nb)
      acc[mt][nb] = (floatx4){0.f, 0.f, 0.f, 0.f};

  short8 aC[4], bC[4], aN[4], bN[4];

#define C4_LOAD(KK, A, BV)                                                    \
  {                                                                           \
    int tap_ = (KK) * 2 + (lk >> 1);                                          \
    if (tap_ > 8) tap_ = 8;                                                   \
    const int dy_ = tap_ / 3, dx_ = tap_ - dy_ * 3;                           \
    const int c0_ = (lk & 1) << 3;                                            \
    const u16* rowp_ = hb + (size_t)(((y + dy_) * 66) + lm + dx_) * 16 + c0_; \
    A[0] = *(const short8*)(rowp_);                                           \
    A[1] = *(const short8*)(rowp_ + 16 * 16);                                 \
    A[2] = *(const short8*)(rowp_ + 32 * 16);                                 \
    A[3] = *(const short8*)(rowp_ + 48 * 16);                                 \
    const u16* bp_ = Bsw4 + ((((KK) * 4 + lk) * 64) + lm) * 8;                \
    BV[0] = *(const short8*)(bp_);                                            \
    BV[1] = *(const short8*)(bp_ + 128);                                      \
    BV[2] = *(const short8*)(bp_ + 256);                                      \
    BV[3] = *(const short8*)(bp_ + 384);                                      \
  }

  C4_LOAD(0, aC, bC)
#pragma unroll
  for (int kk = 0; kk < 5; ++kk) {
    if (kk < 4) C4_LOAD(kk + 1, aN, bN)
#pragma unroll
    for (int mt = 0; mt < 4; ++mt)
#pragma unroll
      for (int nb = 0; nb < 4; ++nb)
        acc[mt][nb] = __builtin_amdgcn_mfma_f32_16x16x32_bf16(aC[mt], bC[nb], acc[mt][nb], 0, 0, 0);
#pragma unroll
    for (int i = 0; i < 4; ++i) { aC[i] = aN[i]; bC[i] = bN[i]; }
  }
#undef C4_LOAD

#pragma unroll
  for (int mt = 0; mt < 4; ++mt)
#pragma unroll
    for (int nb = 0; nb < 4; ++nb) {
      u16* dst = h4 + ((size_t)(b * 64 + nb * 16 + lm) << 12) + (y << 6) + mt * 16 + (lk << 2);
      floatx4 v = acc[mt][nb];
      *(ushort4*)dst = make_ushort4(f2bf(v.x), f2bf(v.y), f2bf(v.z), f2bf(v.w));
    }

  __shared__ float lsum[4][64], lsq[4][64];
  float s[4], s2[4];
#pragma unroll
  for (int nb = 0; nb < 4; ++nb) {
    s[nb] = 0.f; s2[nb] = 0.f;
#pragma unroll
    for (int mt = 0; mt < 4; ++mt) {
      floatx4 a = acc[mt][nb];
      s[nb] += a.x + a.y + a.z + a.w;
      s2[nb] += a.x * a.x + a.y * a.y + a.z * a.z + a.w * a.w;
    }
    s[nb] += __shfl_xor(s[nb], 16, 64);  s[nb] += __shfl_xor(s[nb], 32, 64);
    s2[nb] += __shfl_xor(s2[nb], 16, 64); s2[nb] += __shfl_xor(s2[nb], 32, 64);
  }
  if (lk == 0) {
#pragma unroll
    for (int nb = 0; nb < 4; ++nb) { lsum[w][nb * 16 + lm] = s[nb]; lsq[w][nb * 16 + lm] = s2[nb]; }
  }
  __syncthreads();
  if (tid < 64) atomicAdd(&sum4[tid], lsum[0][tid] + lsum[1][tid] + lsum[2][tid] + lsum[3][tid]);
  else if (tid < 128) { int o = tid - 64; atomicAdd(&sq4[o], lsq[0][o] + lsq[1][o] + lsq[2][o] + lsq[3][o]); }
}

// ---------------------------------------------------------------- final: BN4 + residual + relu (h4 bf16 -> out fp32)
__global__ __launch_bounds__(256) void final_k(const u16* __restrict__ h4,
                                               float* __restrict__ out,
                                               const float* __restrict__ x,
                                               const float* __restrict__ sum4, const float* __restrict__ sq4,
                                               const float* __restrict__ g4, const float* __restrict__ b4) {
  __shared__ float s_scale[64], s_shift[64];
  int tid = threadIdx.x;
  if (tid < 64) {
    float m = sum4[tid] / BN_N;
    float var = sq4[tid] / BN_N - m * m;
    float sc = g4[tid] * rsqrtf(var + 1e-5f);
    s_scale[tid] = sc;
    s_shift[tid] = b4[tid] - m * sc;
  }
  __syncthreads();
  int i = (blockIdx.x * 256 + tid) * 4;
  int c = (i >> 12) & 63;
  ushort4 q = *(const ushort4*)(h4 + i);
  float4 xv = *(const float4*)(x + i);
  float sc = s_scale[c], sh = s_shift[c];
  float4 v;
  v.x = fmaxf(bf2f(q.x) * sc + sh + xv.x, 0.f);
  v.y = fmaxf(bf2f(q.y) * sc + sh + xv.y, 0.f);
  v.z = fmaxf(bf2f(q.z) * sc + sh + xv.z, 0.f);
  v.w = fmaxf(bf2f(q.w) * sc + sh + xv.w, 0.f);
  *(float4*)(out + i) = v;
}

extern "C" void kernel_launch(void* const* d_in, const int* in_sizes, int n_in,
                              void* d_out, int out_size, void* d_ws, size_t ws_size,
                              hipStream_t stream) {
  const float* x  = (const float*)d_in[0];
  const float* w1 = (const float*)d_in[1];
  const float* g1 = (const float*)d_in[2];
  const float* b1 = (const float*)d_in[3];
  const float* w2 = (const float*)d_in[4];
  const float* g2 = (const float*)d_in[5];
  const float* b2 = (const float*)d_in[6];
  const float* ow = (const float*)d_in[7];
  const float* ob = (const float*)d_in[8];
  const float* w3 = (const float*)d_in[9];
  const float* g3 = (const float*)d_in[10];
  const float* b3 = (const float*)d_in[11];
  const float* w4 = (const float*)d_in[12];
  const float* g4 = (const float*)d_in[13];
  const float* b4 = (const float*)d_in[14];
  float* out = (float*)d_out;
  float* ws = (float*)d_ws;

  // workspace layout (float offsets):
  //   offs  (64,18,4096) fp32          4,718,592   dead after deform -> h4 (bf16) overlays
  //   wsd   NHWC fp32 (64,4096,16)     4,194,304
  //   ws2   NHWC fp32 (64,4096,16)     4,194,304
  //   h2p   padded NHWC bf16 region    4,460,544 floats reserved (uses half);
  //         h3p SHARES it (borders from one memset; interior rewritten later)
  //   stats 320
  //   Bsw(36864) Bsw4(10240) Bsw3(2560) BswO(5120)  u16
  // xp (bf16 input) overlays offs+wsd+ws2-head; dead after conv1.
  // h1 (bf16 NCHW conv1 raw) lives in d_out; dead before final_k writes.
  float* offs = ws;
  float* wsd  = offs + 4718592;
  float* ws2  = wsd + 4194304;
  float* h2pf = ws2 + 4194304;
  float* stats = h2pf + 4460544;
  float* sum1 = stats, *sq1 = stats + 64;
  float* sum2 = stats + 128, *sq2 = stats + 144;
  float* sum3 = stats + 160, *sq3 = stats + 176;
  float* sum4 = stats + 192, *sq4 = stats + 256;
  u16* xp   = (u16*)ws;
  u16* Bsw  = (u16*)(stats + 320);
  u16* Bsw4 = Bsw + 36864;
  u16* Bsw3 = Bsw4 + 10240;
  u16* BswO = Bsw3 + 2560;
  u16* h2p  = (u16*)h2pf;    // bf16 padded NHWC (64,66,66,16); doubles as h3p
  u16* h4   = (u16*)offs;    // bf16 NCHW conv4 raw, overlays dead offs
  u16* h1   = (u16*)out;     // bf16 NCHW conv1 raw, in d_out

  hipMemsetAsync(stats, 0, 320 * sizeof(float), stream);
  hipMemsetAsync(h2p, 0, 4460544 * sizeof(u16), stream);

  prep_w_k<<<144, 256, 0, stream>>>(w1, Bsw);
  prep_w4_k<<<40, 256, 0, stream>>>(w4, Bsw4);
  prep_w3_k<<<10, 256, 0, stream>>>(w3, Bsw3);
  prep_wo_k<<<20, 256, 0, stream>>>(ow, BswO);
  prep_x_k<<<dim3(66, 64), 256, 0, stream>>>(x, xp);
  conv1_mfma<<<1024, 256, 0, stream>>>(xp, Bsw, h1, sum1, sq1);
  conv2_k<<<1024, 256, 0, stream>>>(h1, w2, sum1, sq1, g1, b1, ws2, sum2, sq2);
  bnrelu2_k<<<1024, 256, 0, stream>>>(ws2, sum2, sq2, g2, b2, h2p);
  offconv_mfma<<<1024, 256, 0, stream>>>(h2p, BswO, ob, offs);
  deform_mfma<<<1024, 256, 0, stream>>>(h2p, offs, Bsw3, wsd, sum3, sq3);
  bnrelu3_k<<<1024, 256, 0, stream>>>(wsd, sum3, sq3, g3, b3, h2p /* = h3p */);
  conv4_mfma<<<1024, 256, 0, stream>>>(h2p, Bsw4, h4, sum4, sq4);
  final_k<<<16384, 256, 0, stream>>>(h4, out, x, sum4, sq4, g4, b4);
}

// Round 6
// 334.877 us; speedup vs baseline: 6.6921x; 1.0795x over previous
//
#include <hip/hip_runtime.h>

// B=64, Cin=P=64, H=W=64, mid C=16, offsets C=18, K=3x3.  BN n = 262144
#define BN_N 262144.0f

typedef unsigned short u16;
typedef __attribute__((ext_vector_type(8))) short short8;   // 8 x bf16
typedef __attribute__((ext_vector_type(4))) float floatx4;

// xp: padded NHWC bf16, 64 ch/px, XOR-swizzled 16B chunks. Row pitch 66*64.
#define RP1 4224
#define IS1 278784          // 66*RP1
// h2p/h3p: padded NHWC bf16, 16 ch/px padded to 24 (2-way LDS banks). Row pitch 66*24.
#define RP2 1584
#define IS2 104544          // 66*RP2
#define H2P_TOTAL 6690816   // 64*IS2 u16

static __device__ __forceinline__ u16 f2bf(float f) {
  union { float f; unsigned u; } v; v.f = f;
  unsigned u = v.u;
  return (u16)((u + 0x7FFFu + ((u >> 16) & 1u)) >> 16);
}
static __device__ __forceinline__ float bf2f(u16 h) {
  union { unsigned u; float f; } v; v.u = ((unsigned)h) << 16;
  return v.f;
}
// async global->LDS, 16 B per lane; LDS dest = wave-uniform base + lane*16
static __device__ __forceinline__ void cp16(const u16* g, u16* l) {
  __builtin_amdgcn_global_load_lds((const __attribute__((address_space(1))) unsigned int*)g,
                                   (__attribute__((address_space(3))) unsigned int*)l, 16, 0, 0);
}

// ---------------------------------------------------------------- prep: w1 -> swizzled bf16 B (conv1, K=576)
__global__ __launch_bounds__(256) void prep_w_k(const float* __restrict__ w1,
                                                u16* __restrict__ Bsw) {
  int d = blockIdx.x * 256 + threadIdx.x;   // 0..36863
  int kin = d & 7, n = (d >> 3) & 63, kgrp = (d >> 9) & 3, kc = d >> 11;
  int k = kc * 32 + kgrp * 8 + kin;
  int tap = k >> 6, c = k & 63;
  Bsw[d] = f2bf(w1[n * 576 + c * 9 + tap]);
}

// ---------------------------------------------------------------- prep: w4 -> swizzled bf16 B (conv4, K=144->160)
__global__ __launch_bounds__(256) void prep_w4_k(const float* __restrict__ w4,
                                                 u16* __restrict__ Bsw4) {
  int d = blockIdx.x * 256 + threadIdx.x;   // 0..10239
  if (d >= 10240) return;
  int kin = d & 7, n = (d >> 3) & 63, lk = (d >> 9) & 3, kk = d >> 11;
  int tap = kk * 2 + (lk >> 1);
  int c = ((lk & 1) << 3) + kin;
  float v = (tap < 9) ? w4[n * 144 + c * 9 + tap] : 0.f;
  Bsw4[d] = f2bf(v);
}

// ---------------------------------------------------------------- prep: w3 -> swizzled bf16 B (deform, K=144->160, N=16)
__global__ __launch_bounds__(256) void prep_w3_k(const float* __restrict__ w3,
                                                 u16* __restrict__ Bsw3) {
  int d = blockIdx.x * 256 + threadIdx.x;   // 0..2559
  if (d >= 2560) return;
  int kin = d & 7, n = (d >> 3) & 15, lk = (d >> 7) & 3, kk = d >> 9;
  int k = kk * 32 + lk * 8 + kin;
  int tap = k >> 4, c = k & 15;
  float v = (tap < 9) ? w3[n * 144 + c * 9 + tap] : 0.f;
  Bsw3[d] = f2bf(v);
}

// ---------------------------------------------------------------- prep: ow -> swizzled bf16 B (offconv, K=144->160, N=18->32)
__global__ __launch_bounds__(256) void prep_wo_k(const float* __restrict__ ow,
                                                 u16* __restrict__ BswO) {
  int d = blockIdx.x * 256 + threadIdx.x;   // 0..5119
  if (d >= 5120) return;
  int kin = d & 7, n = (d >> 3) & 31, lk = (d >> 8) & 3, kk = d >> 10;
  int tap = kk * 2 + (lk >> 1);
  int c = ((lk & 1) << 3) + kin;
  float v = (tap < 9 && n < 18) ? ow[n * 144 + c * 9 + tap] : 0.f;
  BswO[d] = f2bf(v);
}

// ---------------------------------------------------------------- prep: x -> padded NHWC bf16, XOR-swizzled chunks
// logical chunk (c/8) of pixel pxp stored at phys chunk (c/8)^(pxp&7)
__global__ __launch_bounds__(256) void prep_x_k(const float* __restrict__ x,
                                                u16* __restrict__ xp) {
  int yp = blockIdx.x;   // 0..65
  int b = blockIdx.y;
  int tid = threadIdx.x;
  u16* rowbase = xp + (size_t)(b * 66 + yp) * RP1;
  if (yp == 0 || yp == 65) {
    for (int i = tid; i < RP1 / 4; i += 256)
      ((ushort4*)rowbase)[i] = make_ushort4(0, 0, 0, 0);
    return;
  }
  int y = yp - 1;
  __shared__ __align__(16) u16 s[64][72];
  for (int i = tid; i < 4096; i += 256) {
    int c = i >> 6, xx = i & 63;
    s[xx][c] = f2bf(x[((b * 64 + c) << 12) + (y << 6) + xx]);
  }
  if (tid < 128) {                 // zero pad columns (px 0 and 65)
    int c = tid & 63;
    int pxp = (tid >> 6) ? 65 : 0;
    rowbase[pxp * 64 + c] = 0;
  }
  __syncthreads();
  for (int j = tid; j < 512; j += 256) {       // 64 px x 8 chunks of 16 B
    int xx = j >> 3, chunk = j & 7;
    int pxp = xx + 1;
    int ph = chunk ^ (pxp & 7);
    *(short8*)(rowbase + pxp * 64 + ph * 8) = *(const short8*)(&s[xx][chunk * 8]);
  }
}

// ---------------------------------------------------------------- conv1: LDS-staged implicit GEMM + fused stats1
// Block = 4 output rows; LDS holds 6 padded input rows (50 KB, async DMA).
// K-loop: A from LDS (ds_read_b128, 2-way banks via XOR swizzle), B from global.
__global__ __launch_bounds__(256) void conv1_mfma(const u16* __restrict__ xp,
                                                  const u16* __restrict__ Bsw,
                                                  u16* __restrict__ h1,        // bf16 NCHW raw
                                                  float* __restrict__ sum1, float* __restrict__ sq1) {
  __shared__ __align__(16) u16 lA[25600];     // 50 segs x 512 u16 (6 rows + overread)
  const int tid = threadIdx.x;
  const int w = tid >> 6, l = tid & 63;
  const int lm = l & 15, lk = l >> 4;
  const int b = blockIdx.x >> 4;
  const int y0 = (blockIdx.x & 15) << 2;
  const int y = y0 + w;                        // wave's output row
  const u16* src = xp + ((size_t)b * 66 + y0) * RP1;
  for (int seg = w; seg < 50; seg += 4)
    cp16(src + seg * 512 + l * 8, lA + seg * 512);
  __syncthreads();                             // vmcnt drain + barrier

  floatx4 acc[4][4];
#pragma unroll
  for (int mt = 0; mt < 4; ++mt)
#pragma unroll
    for (int nb = 0; nb < 4; ++nb)
      acc[mt][nb] = (floatx4){0.f, 0.f, 0.f, 0.f};

  short8 bC[4], bN[4];
#define BLOAD(KK, BV)                                                 \
  { const u16* bp_ = Bsw + ((((KK) * 4 + lk) * 64) + lm) * 8;         \
    BV[0] = *(const short8*)(bp_);                                    \
    BV[1] = *(const short8*)(bp_ + 128);                              \
    BV[2] = *(const short8*)(bp_ + 256);                              \
    BV[3] = *(const short8*)(bp_ + 384); }

  BLOAD(0, bC)
#pragma unroll
  for (int kk = 0; kk < 18; ++kk) {
    if (kk < 17) BLOAD(kk + 1, bN)
    const int tap = kk >> 1;
    const int dy = (tap < 3) ? 0 : ((tap < 6) ? 1 : 2);
    const int dx = tap - dy * 3;
    const int chunk = ((kk & 1) << 2) + lk;    // logical 16B chunk 0..7
    const int rowoff = (w + dy) * RP1;
    short8 aF[4];
#pragma unroll
    for (int mt = 0; mt < 4; ++mt) {
      int pxp = mt * 16 + lm + dx;
      int ph = chunk ^ (pxp & 7);
      aF[mt] = *(const short8*)(lA + rowoff + pxp * 64 + ph * 8);
    }
#pragma unroll
    for (int mt = 0; mt < 4; ++mt)
#pragma unroll
      for (int nb = 0; nb < 4; ++nb)
        acc[mt][nb] = __builtin_amdgcn_mfma_f32_16x16x32_bf16(aF[mt], bC[nb], acc[mt][nb], 0, 0, 0);
#pragma unroll
    for (int i = 0; i < 4; ++i) bC[i] = bN[i];
  }
#undef BLOAD

  // store bf16 NCHW: lane oc = nb*16+lm, pixel x = mt*16 + lk*4 + reg
#pragma unroll
  for (int mt = 0; mt < 4; ++mt)
#pragma unroll
    for (int nb = 0; nb < 4; ++nb) {
      u16* dst = h1 + ((size_t)(b * 64 + nb * 16 + lm) << 12) + (y << 6) + mt * 16 + (lk << 2);
      floatx4 v = acc[mt][nb];
      *(ushort4*)dst = make_ushort4(f2bf(v.x), f2bf(v.y), f2bf(v.z), f2bf(v.w));
    }

  // fused stats1 (reuse lA as float scratch after barrier)
  __syncthreads();
  float* LS = (float*)lA;        // [4][64]
  float* LQ = LS + 256;
  float s[4], s2[4];
#pragma unroll
  for (int nb = 0; nb < 4; ++nb) {
    s[nb] = 0.f; s2[nb] = 0.f;
#pragma unroll
    for (int mt = 0; mt < 4; ++mt) {
      floatx4 a = acc[mt][nb];
      s[nb] += a.x + a.y + a.z + a.w;
      s2[nb] += a.x * a.x + a.y * a.y + a.z * a.z + a.w * a.w;
    }
    s[nb] += __shfl_xor(s[nb], 16, 64);  s[nb] += __shfl_xor(s[nb], 32, 64);
    s2[nb] += __shfl_xor(s2[nb], 16, 64); s2[nb] += __shfl_xor(s2[nb], 32, 64);
  }
  if (lk == 0) {
#pragma unroll
    for (int nb = 0; nb < 4; ++nb) { LS[w * 64 + nb * 16 + lm] = s[nb]; LQ[w * 64 + nb * 16 + lm] = s2[nb]; }
  }
  __syncthreads();
  if (tid < 64) atomicAdd(&sum1[tid], LS[tid] + LS[64 + tid] + LS[128 + tid] + LS[192 + tid]);
  else if (tid < 128) { int o = tid - 64; atomicAdd(&sq1[o], LQ[o] + LQ[64 + o] + LQ[128 + o] + LQ[192 + o]); }
}

// ---------------------------------------------------------------- conv2: 1x1 64->16 (bf16 h1 in), BN1+relu, NHWC out + stats2
__global__ __launch_bounds__(256) void conv2_k(const u16* __restrict__ h1,
                                               const float* __restrict__ w2,
                                               const float* __restrict__ sum1, const float* __restrict__ sq1,
                                               const float* __restrict__ g1, const float* __restrict__ b1,
                                               float* __restrict__ out,        // NHWC (64,4096,16)
                                               float* __restrict__ sum2, float* __restrict__ sq2) {
  __shared__ float s_wt[64 * 16];
  __shared__ float s_scale[64], s_shift[64];
  __shared__ float ls[4][16], lsq[4][16];
  int tid = threadIdx.x;
  for (int i = tid; i < 1024; i += 256) {
    int o = i >> 6, c = i & 63;
    s_wt[c * 16 + o] = w2[i];
  }
  if (tid < 64) {
    float m = sum1[tid] / BN_N;
    float var = sq1[tid] / BN_N - m * m;
    float sc = g1[tid] * rsqrtf(var + 1e-5f);
    s_scale[tid] = sc;
    s_shift[tid] = b1[tid] - m * sc;
  }
  __syncthreads();
  int p = blockIdx.x * 256 + tid;
  int b = p >> 12, r = p & 4095;
  const u16* src = h1 + ((size_t)b << 18) + r;
  float acc[16];
#pragma unroll
  for (int o = 0; o < 16; ++o) acc[o] = 0.f;
  for (int c = 0; c < 64; ++c) {
    float v = bf2f(src[c << 12]);
    v = fmaxf(v * s_scale[c] + s_shift[c], 0.f);
    const float* wp = &s_wt[c * 16];
    float4 w0 = *(const float4*)wp;
    float4 w1 = *(const float4*)(wp + 4);
    float4 w2v = *(const float4*)(wp + 8);
    float4 w3v = *(const float4*)(wp + 12);
    acc[0] += w0.x * v;  acc[1] += w0.y * v;  acc[2] += w0.z * v;  acc[3] += w0.w * v;
    acc[4] += w1.x * v;  acc[5] += w1.y * v;  acc[6] += w1.z * v;  acc[7] += w1.w * v;
    acc[8] += w2v.x * v; acc[9] += w2v.y * v; acc[10] += w2v.z * v; acc[11] += w2v.w * v;
    acc[12] += w3v.x * v; acc[13] += w3v.y * v; acc[14] += w3v.z * v; acc[15] += w3v.w * v;
  }
  float* dst = out + (size_t)p * 16;
#pragma unroll
  for (int c4 = 0; c4 < 4; ++c4)
    *(float4*)(dst + c4 * 4) = make_float4(acc[c4*4], acc[c4*4+1], acc[c4*4+2], acc[c4*4+3]);
  int lane = tid & 63, wv = tid >> 6;
#pragma unroll
  for (int o = 0; o < 16; ++o) {
    float s = acc[o], s2 = acc[o] * acc[o];
#pragma unroll
    for (int off = 32; off > 0; off >>= 1) {
      s += __shfl_down(s, off, 64);
      s2 += __shfl_down(s2, off, 64);
    }
    if (lane == 0) { ls[wv][o] = s; lsq[wv][o] = s2; }
  }
  __syncthreads();
  if (tid < 16) atomicAdd(&sum2[tid], ls[0][tid] + ls[1][tid] + ls[2][tid] + ls[3][tid]);
  else if (tid < 32) {
    int o = tid - 16;
    atomicAdd(&sq2[o], lsq[0][o] + lsq[1][o] + lsq[2][o] + lsq[3][o]);
  }
}

// ---------------------------------------------------------------- BN2+relu: NHWC fp32 -> padded pitch-24 bf16 h2p
__global__ __launch_bounds__(256) void bnrelu2_k(const float* __restrict__ ws2,
                                                 const float* __restrict__ sum2, const float* __restrict__ sq2,
                                                 const float* __restrict__ g2, const float* __restrict__ b2,
                                                 u16* __restrict__ h2p) {
  __shared__ float s_scale[16], s_shift[16];
  int tid = threadIdx.x;
  if (tid < 16) {
    float m = sum2[tid] / BN_N;
    float var = sq2[tid] / BN_N - m * m;
    float sc = g2[tid] * rsqrtf(var + 1e-5f);
    s_scale[tid] = sc;
    s_shift[tid] = b2[tid] - m * sc;
  }
  __syncthreads();
  int p = blockIdx.x * 256 + tid;
  int b = p >> 12, r = p & 4095;
  int y = r >> 6, xx = r & 63;
  const float* src = ws2 + (size_t)p * 16;
  u16* dst = h2p + (size_t)(b * 66 + y + 1) * RP2 + (xx + 1) * 24;
#pragma unroll
  for (int c4 = 0; c4 < 4; ++c4) {
    float4 v = *(const float4*)(src + c4 * 4);
    u16 o0 = f2bf(fmaxf(v.x * s_scale[c4*4]   + s_shift[c4*4],   0.f));
    u16 o1 = f2bf(fmaxf(v.y * s_scale[c4*4+1] + s_shift[c4*4+1], 0.f));
    u16 o2 = f2bf(fmaxf(v.z * s_scale[c4*4+2] + s_shift[c4*4+2], 0.f));
    u16 o3 = f2bf(fmaxf(v.w * s_scale[c4*4+3] + s_shift[c4*4+3], 0.f));
    *(ushort4*)(dst + c4 * 4) = make_ushort4(o0, o1, o2, o3);
  }
}

// ---------------------------------------------------------------- offconv: LDS-staged implicit GEMM, N=32(18), K=160
__global__ __launch_bounds__(256) void offconv_mfma(const u16* __restrict__ h2p,
                                                    const u16* __restrict__ BswO,
                                                    const float* __restrict__ ob,
                                                    float* __restrict__ offs) {   // (64,18,64,64)
  __shared__ __align__(16) u16 lA[9728];    // 19 segs (6 rows pitch-24 + overread)
  __shared__ __align__(16) u16 lB[5120];    // 10 segs
  const int tid = threadIdx.x;
  const int w = tid >> 6, l = tid & 63;
  const int lm = l & 15, lk = l >> 4;
  const int b = blockIdx.x >> 4;
  const int y0 = (blockIdx.x & 15) << 2;
  const int y = y0 + w;
  const u16* src = h2p + ((size_t)b * 66 + y0) * RP2;
  for (int seg = w; seg < 19; seg += 4) cp16(src + seg * 512 + l * 8, lA + seg * 512);
  for (int seg = w; seg < 10; seg += 4) cp16(BswO + seg * 512 + l * 8, lB + seg * 512);
  __syncthreads();

  floatx4 acc[4][2];
#pragma unroll
  for (int mt = 0; mt < 4; ++mt)
#pragma unroll
    for (int nb = 0; nb < 2; ++nb)
      acc[mt][nb] = (floatx4){0.f, 0.f, 0.f, 0.f};

#pragma unroll
  for (int kk = 0; kk < 5; ++kk) {
    int tap = kk * 2 + (lk >> 1);
    if (tap > 8) tap = 8;
    const int dy = tap / 3, dx = tap - dy * 3;
    const int c0 = (lk & 1) << 3;
    const int rowoff = (w + dy) * RP2;
    short8 aF[4], bF[2];
#pragma unroll
    for (int mt = 0; mt < 4; ++mt)
      aF[mt] = *(const short8*)(lA + rowoff + (mt * 16 + lm + dx) * 24 + c0);
    const u16* bp = lB + (((kk * 4 + lk) * 32) + lm) * 8;
    bF[0] = *(const short8*)(bp);
    bF[1] = *(const short8*)(bp + 128);
#pragma unroll
    for (int mt = 0; mt < 4; ++mt)
#pragma unroll
      for (int nb = 0; nb < 2; ++nb)
        acc[mt][nb] = __builtin_amdgcn_mfma_f32_16x16x32_bf16(aF[mt], bF[nb], acc[mt][nb], 0, 0, 0);
  }

#pragma unroll
  for (int mt = 0; mt < 4; ++mt)
#pragma unroll
    for (int nb = 0; nb < 2; ++nb) {
      int oc = nb * 16 + lm;
      if (oc < 18) {
        float bias = ob[oc];
        floatx4 v = acc[mt][nb];
        v.x += bias; v.y += bias; v.z += bias; v.w += bias;
        float* dst = offs + (size_t)b * 73728 + (oc << 12) + (y << 6) + mt * 16 + (lk << 2);
        *(floatx4*)dst = v;
      }
    }
}

// ---------------------------------------------------------------- deform: bilinear -> in-register A-frag -> MFMA (pitch-24 img)
__global__ __launch_bounds__(256) void deform_mfma(const u16* __restrict__ h2p,
                                                   const float* __restrict__ offs,
                                                   const u16* __restrict__ Bsw3,
                                                   float* __restrict__ out,      // NHWC (64,4096,16)
                                                   float* __restrict__ sum3, float* __restrict__ sq3) {
  const int tid = threadIdx.x;
  const int w = tid >> 6, l = tid & 63;
  const int lm = l & 15, lk = l >> 4;
  const int pbase = blockIdx.x * 256 + w * 64;
  const int b = pbase >> 12;
  const u16* img = h2p + (size_t)b * IS2;
  const float* offp = offs + (size_t)b * 73728;

  short8 bf[5];
#pragma unroll
  for (int kk = 0; kk < 5; ++kk)
    bf[kk] = *(const short8*)(Bsw3 + (((kk * 4 + lk) * 16) + lm) * 8);

  floatx4 acc[4];
#pragma unroll
  for (int mt = 0; mt < 4; ++mt) acc[mt] = (floatx4){0.f, 0.f, 0.f, 0.f};

#pragma unroll
  for (int mt = 0; mt < 4; ++mt) {
    const int p = pbase + mt * 16 + lm;
    const int r = p & 4095;
    const int y = r >> 6, x = r & 63;
#pragma unroll
    for (int kk = 0; kk < 5; ++kk) {
      const int k0 = kk * 32 + lk * 8;
      int tap = k0 >> 4;
      const int c0 = k0 & 15;
      if (tap > 8) tap = 8;
      const int dy = tap / 3, dx = tap - dy * 3;
      float offy = offp[(tap << 12) + r];
      float offx = offp[((tap + 9) << 12) + r];
      float py = (float)(y + dy) + offy;
      float px = (float)(x + dx) + offx;
      py = fminf(fmaxf(py, 0.f), 65.f);
      px = fminf(fmaxf(px, 0.f), 65.f);
      float y0f = floorf(py), x0f = floorf(px);
      int y0 = (int)y0f, x0 = (int)x0f;
      int y1 = min(y0 + 1, 65), x1 = min(x0 + 1, 65);
      float wy = py - y0f, wx = px - x0f;
      float w00 = (1.f - wy) * (1.f - wx), w01 = (1.f - wy) * wx;
      float w10 = wy * (1.f - wx),         w11 = wy * wx;
      short8 v00 = *(const short8*)(img + (y0 * 66 + x0) * 24 + c0);
      short8 v01 = *(const short8*)(img + (y0 * 66 + x1) * 24 + c0);
      short8 v10 = *(const short8*)(img + (y1 * 66 + x0) * 24 + c0);
      short8 v11 = *(const short8*)(img + (y1 * 66 + x1) * 24 + c0);
      short8 a;
#pragma unroll
      for (int j = 0; j < 8; ++j) {
        float s = bf2f((u16)v00[j]) * w00 + bf2f((u16)v01[j]) * w01
                + bf2f((u16)v10[j]) * w10 + bf2f((u16)v11[j]) * w11;
        a[j] = (short)f2bf(s);
      }
      acc[mt] = __builtin_amdgcn_mfma_f32_16x16x32_bf16(a, bf[kk], acc[mt], 0, 0, 0);
    }
  }

  float s = 0.f, s2 = 0.f;
#pragma unroll
  for (int mt = 0; mt < 4; ++mt) {
    floatx4 a = acc[mt];
    s += a.x + a.y + a.z + a.w;
    s2 += a.x * a.x + a.y * a.y + a.z * a.z + a.w * a.w;
#pragma unroll
    for (int reg = 0; reg < 4; ++reg) {
      int pp = pbase + mt * 16 + lk * 4 + reg;
      out[(size_t)pp * 16 + lm] = acc[mt][reg];
    }
  }
  __shared__ float ls[4][16], lsq[4][16];
  s += __shfl_xor(s, 16, 64);  s += __shfl_xor(s, 32, 64);
  s2 += __shfl_xor(s2, 16, 64); s2 += __shfl_xor(s2, 32, 64);
  if (lk == 0) { ls[w][lm] = s; lsq[w][lm] = s2; }
  __syncthreads();
  if (tid < 16) atomicAdd(&sum3[tid], ls[0][tid] + ls[1][tid] + ls[2][tid] + ls[3][tid]);
  else if (tid < 32) {
    int o = tid - 16;
    atomicAdd(&sq3[o], lsq[0][o] + lsq[1][o] + lsq[2][o] + lsq[3][o]);
  }
}

// ---------------------------------------------------------------- BN3+relu: NHWC fp32 -> padded pitch-24 bf16 h3p
__global__ __launch_bounds__(256) void bnrelu3_k(const float* __restrict__ wsd,
                                                 const float* __restrict__ sum3, const float* __restrict__ sq3,
                                                 const float* __restrict__ g3, const float* __restrict__ b3,
                                                 u16* __restrict__ h3p) {
  __shared__ float s_scale[16], s_shift[16];
  int tid = threadIdx.x;
  if (tid < 16) {
    float m = sum3[tid] / BN_N;
    float var = sq3[tid] / BN_N - m * m;
    float sc = g3[tid] * rsqrtf(var + 1e-5f);
    s_scale[tid] = sc;
    s_shift[tid] = b3[tid] - m * sc;
  }
  __syncthreads();
  int p = blockIdx.x * 256 + tid;
  int b = p >> 12, r = p & 4095;
  int y = r >> 6, xx = r & 63;
  const float* src = wsd + (size_t)p * 16;
  u16* dst = h3p + (size_t)(b * 66 + y + 1) * RP2 + (xx + 1) * 24;
#pragma unroll
  for (int c4 = 0; c4 < 4; ++c4) {
    float4 v = *(const float4*)(src + c4 * 4);
    u16 o0 = f2bf(fmaxf(v.x * s_scale[c4*4]   + s_shift[c4*4],   0.f));
    u16 o1 = f2bf(fmaxf(v.y * s_scale[c4*4+1] + s_shift[c4*4+1], 0.f));
    u16 o2 = f2bf(fmaxf(v.z * s_scale[c4*4+2] + s_shift[c4*4+2], 0.f));
    u16 o3 = f2bf(fmaxf(v.w * s_scale[c4*4+3] + s_shift[c4*4+3], 0.f));
    *(ushort4*)(dst + c4 * 4) = make_ushort4(o0, o1, o2, o3);
  }
}

// ---------------------------------------------------------------- conv4: LDS-staged implicit GEMM (A+B in LDS) + stats4
__global__ __launch_bounds__(256) void conv4_mfma(const u16* __restrict__ h3p,
                                                  const u16* __restrict__ Bsw4,
                                                  u16* __restrict__ h4,
                                                  float* __restrict__ sum4, float* __restrict__ sq4) {
  __shared__ __align__(16) u16 lA[9728];     // 19 segs
  __shared__ __align__(16) u16 lB[10240];    // 20 segs
  const int tid = threadIdx.x;
  const int w = tid >> 6, l = tid & 63;
  const int lm = l & 15, lk = l >> 4;
  const int b = blockIdx.x >> 4;
  const int y0 = (blockIdx.x & 15) << 2;
  const int y = y0 + w;
  const u16* src = h3p + ((size_t)b * 66 + y0) * RP2;
  for (int seg = w; seg < 19; seg += 4) cp16(src + seg * 512 + l * 8, lA + seg * 512);
  for (int seg = w; seg < 20; seg += 4) cp16(Bsw4 + seg * 512 + l * 8, lB + seg * 512);
  __syncthreads();

  floatx4 acc[4][4];
#pragma unroll
  for (int mt = 0; mt < 4; ++mt)
#pragma unroll
    for (int nb = 0; nb < 4; ++nb)
      acc[mt][nb] = (floatx4){0.f, 0.f, 0.f, 0.f};

#pragma unroll
  for (int kk = 0; kk < 5; ++kk) {
    int tap = kk * 2 + (lk >> 1);
    if (tap > 8) tap = 8;
    const int dy = tap / 3, dx = tap - dy * 3;
    const int c0 = (lk & 1) << 3;
    const int rowoff = (w + dy) * RP2;
    short8 aF[4], bF[4];
#pragma unroll
    for (int mt = 0; mt < 4; ++mt)
      aF[mt] = *(const short8*)(lA + rowoff + (mt * 16 + lm + dx) * 24 + c0);
    const u16* bp = lB + (((kk * 4 + lk) * 64) + lm) * 8;
    bF[0] = *(const short8*)(bp);
    bF[1] = *(const short8*)(bp + 128);
    bF[2] = *(const short8*)(bp + 256);
    bF[3] = *(const short8*)(bp + 384);
#pragma unroll
    for (int mt = 0; mt < 4; ++mt)
#pragma unroll
      for (int nb = 0; nb < 4; ++nb)
        acc[mt][nb] = __builtin_amdgcn_mfma_f32_16x16x32_bf16(aF[mt], bF[nb], acc[mt][nb], 0, 0, 0);
  }

#pragma unroll
  for (int mt = 0; mt < 4; ++mt)
#pragma unroll
    for (int nb = 0; nb < 4; ++nb) {
      u16* dst = h4 + ((size_t)(b * 64 + nb * 16 + lm) << 12) + (y << 6) + mt * 16 + (lk << 2);
      floatx4 v = acc[mt][nb];
      *(ushort4*)dst = make_ushort4(f2bf(v.x), f2bf(v.y), f2bf(v.z), f2bf(v.w));
    }

  // fused stats4 (reuse lA after barrier)
  __syncthreads();
  float* LS = (float*)lA;
  float* LQ = LS + 256;
  float s[4], s2[4];
#pragma unroll
  for (int nb = 0; nb < 4; ++nb) {
    s[nb] = 0.f; s2[nb] = 0.f;
#pragma unroll
    for (int mt = 0; mt < 4; ++mt) {
      floatx4 a = acc[mt][nb];
      s[nb] += a.x + a.y + a.z + a.w;
      s2[nb] += a.x * a.x + a.y * a.y + a.z * a.z + a.w * a.w;
    }
    s[nb] += __shfl_xor(s[nb], 16, 64);  s[nb] += __shfl_xor(s[nb], 32, 64);
    s2[nb] += __shfl_xor(s2[nb], 16, 64); s2[nb] += __shfl_xor(s2[nb], 32, 64);
  }
  if (lk == 0) {
#pragma unroll
    for (int nb = 0; nb < 4; ++nb) { LS[w * 64 + nb * 16 + lm] = s[nb]; LQ[w * 64 + nb * 16 + lm] = s2[nb]; }
  }
  __syncthreads();
  if (tid < 64) atomicAdd(&sum4[tid], LS[tid] + LS[64 + tid] + LS[128 + tid] + LS[192 + tid]);
  else if (tid < 128) { int o = tid - 64; atomicAdd(&sq4[o], LQ[o] + LQ[64 + o] + LQ[128 + o] + LQ[192 + o]); }
}

// ---------------------------------------------------------------- final: BN4 + residual + relu (h4 bf16 -> out fp32)
__global__ __launch_bounds__(256) void final_k(const u16* __restrict__ h4,
                                               float* __restrict__ out,
                                               const float* __restrict__ x,
                                               const float* __restrict__ sum4, const float* __restrict__ sq4,
                                               const float* __restrict__ g4, const float* __restrict__ b4) {
  __shared__ float s_scale[64], s_shift[64];
  int tid = threadIdx.x;
  if (tid < 64) {
    float m = sum4[tid] / BN_N;
    float var = sq4[tid] / BN_N - m * m;
    float sc = g4[tid] * rsqrtf(var + 1e-5f);
    s_scale[tid] = sc;
    s_shift[tid] = b4[tid] - m * sc;
  }
  __syncthreads();
  int i = (blockIdx.x * 256 + tid) * 4;
  int c = (i >> 12) & 63;
  ushort4 q = *(const ushort4*)(h4 + i);
  float4 xv = *(const float4*)(x + i);
  float sc = s_scale[c], sh = s_shift[c];
  float4 v;
  v.x = fmaxf(bf2f(q.x) * sc + sh + xv.x, 0.f);
  v.y = fmaxf(bf2f(q.y) * sc + sh + xv.y, 0.f);
  v.z = fmaxf(bf2f(q.z) * sc + sh + xv.z, 0.f);
  v.w = fmaxf(bf2f(q.w) * sc + sh + xv.w, 0.f);
  *(float4*)(out + i) = v;
}

extern "C" void kernel_launch(void* const* d_in, const int* in_sizes, int n_in,
                              void* d_out, int out_size, void* d_ws, size_t ws_size,
                              hipStream_t stream) {
  const float* x  = (const float*)d_in[0];
  const float* w1 = (const float*)d_in[1];
  const float* g1 = (const float*)d_in[2];
  const float* b1 = (const float*)d_in[3];
  const float* w2 = (const float*)d_in[4];
  const float* g2 = (const float*)d_in[5];
  const float* b2 = (const float*)d_in[6];
  const float* ow = (const float*)d_in[7];
  const float* ob = (const float*)d_in[8];
  const float* w3 = (const float*)d_in[9];
  const float* g3 = (const float*)d_in[10];
  const float* b3 = (const float*)d_in[11];
  const float* w4 = (const float*)d_in[12];
  const float* g4 = (const float*)d_in[13];
  const float* b4 = (const float*)d_in[14];
  float* out = (float*)d_out;
  float* ws = (float*)d_ws;

  // workspace layout (float offsets):
  //   offs  (64,18,4096) fp32          4,718,592   dead after deform -> h4 (bf16) overlays
  //   wsd   NHWC fp32 (64,4096,16)     4,194,304
  //   ws2   NHWC fp32 (64,4096,16)     4,194,304
  //   h2p   padded pitch-24 bf16       4,460,544 floats reserved (uses 3.35M);
  //         h3p SHARES it (borders from one memset; interior rewritten later)
  //   stats 320
  //   Bsw(36864) Bsw4(10240) Bsw3(2560) BswO(5120)  u16
  // xp (swizzled bf16 input, 17.8M u16) overlays offs+wsd+ws2-head; dead after conv1.
  // h1 (bf16 NCHW conv1 raw) lives in d_out; dead before final_k writes.
  float* offs = ws;
  float* wsd  = offs + 4718592;
  float* ws2  = wsd + 4194304;
  float* h2pf = ws2 + 4194304;
  float* stats = h2pf + 4460544;
  float* sum1 = stats, *sq1 = stats + 64;
  float* sum2 = stats + 128, *sq2 = stats + 144;
  float* sum3 = stats + 160, *sq3 = stats + 176;
  float* sum4 = stats + 192, *sq4 = stats + 256;
  u16* xp   = (u16*)ws;
  u16* Bsw  = (u16*)(stats + 320);
  u16* Bsw4 = Bsw + 36864;
  u16* Bsw3 = Bsw4 + 10240;
  u16* BswO = Bsw3 + 2560;
  u16* h2p  = (u16*)h2pf;    // bf16 padded pitch-24; doubles as h3p
  u16* h4   = (u16*)offs;    // bf16 NCHW conv4 raw, overlays dead offs
  u16* h1   = (u16*)out;     // bf16 NCHW conv1 raw, in d_out

  hipMemsetAsync(stats, 0, 320 * sizeof(float), stream);
  hipMemsetAsync(h2p, 0, (size_t)H2P_TOTAL * sizeof(u16), stream);

  prep_w_k<<<144, 256, 0, stream>>>(w1, Bsw);
  prep_w4_k<<<40, 256, 0, stream>>>(w4, Bsw4);
  prep_w3_k<<<10, 256, 0, stream>>>(w3, Bsw3);
  prep_wo_k<<<20, 256, 0, stream>>>(ow, BswO);
  prep_x_k<<<dim3(66, 64), 256, 0, stream>>>(x, xp);
  conv1_mfma<<<1024, 256, 0, stream>>>(xp, Bsw, h1, sum1, sq1);
  conv2_k<<<1024, 256, 0, stream>>>(h1, w2, sum1, sq1, g1, b1, ws2, sum2, sq2);
  bnrelu2_k<<<1024, 256, 0, stream>>>(ws2, sum2, sq2, g2, b2, h2p);
  offconv_mfma<<<1024, 256, 0, stream>>>(h2p, BswO, ob, offs);
  deform_mfma<<<1024, 256, 0, stream>>>(h2p, offs, Bsw3, wsd, sum3, sq3);
  bnrelu3_k<<<1024, 256, 0, stream>>>(wsd, sum3, sq3, g3, b3, h2p /* = h3p */);
  conv4_mfma<<<1024, 256, 0, stream>>>(h2p, Bsw4, h4, sum4, sq4);
  final_k<<<16384, 256, 0, stream>>>(h4, out, x, sum4, sq4, g4, b4);
}